// Round 10
// baseline (512.023 us; speedup 1.0000x reference)
//
#include <hip/hip_runtime.h>

#define NN 100000
#define NE 3200000
#define NA 60000
#define NB 40000
#define NHID 256
#define NOUT 64

#define RPB 64                    // rows per bucket
#define NBUCK 1563                // ceil(NN/64)
#define PBLK 256                  // partition blocks
#define CHUNK 12500               // NE / PBLK (exact)
#define SCHUNK_SHIFT 13           // 8192-col chunks for L2 locality
#define SBINS 1024                // 64 rows x 16 chunks

typedef unsigned short u16;
typedef unsigned int u32;
typedef __attribute__((ext_vector_type(8))) short short8;
typedef __attribute__((ext_vector_type(4))) float f32x4;

__device__ __forceinline__ float bf2f(u16 u) {
  return __uint_as_float(((u32)u) << 16);
}
__device__ __forceinline__ u16 f2bf(float f) {
  u32 u = __float_as_uint(f);
  u32 r = (u + 0x7fffu + ((u >> 16) & 1u)) >> 16;  // RNE
  return (u16)r;
}
// sign-extend byte b of dw to float
__device__ __forceinline__ float i8f(u32 dw, int b) {
  return (float)((int)(dw << (24 - 8 * b)) >> 24);
}

__device__ __forceinline__ void gload_lds16(const void* gsrc, void* ldst) {
  __builtin_amdgcn_global_load_lds(
      (const __attribute__((address_space(1))) void*)gsrc,
      (__attribute__((address_space(3))) void*)ldst, 16, 0, 0);
}

// ---------------------------------------------------------------------------
// bf16 MFMA GEMM: C = A @ Bt^T + bias.
// QUANT=0: bf16 out (opt relu).
// QUANT=1 (BN=128, N=256): int8 out, per-row-per-64col scale, lane-major pack.
// QUANT=2 (BN=64, N=64): int8 out, per-row scale, lane-major pack.
// ---------------------------------------------------------------------------
template <int BN, int RELU_OUT, int QUANT>
__global__ __launch_bounds__(256) void gemm_mfma(
    const u16* __restrict__ A, const u16* __restrict__ Bt,
    const float* __restrict__ bias, void* __restrict__ Cout,
    float* __restrict__ scales, int M, int N, int K) {
  constexpr int BM = 128;
  constexpr int FI = (BN == 128) ? 4 : 2;
  constexpr int WROWS = FI * 16;
  __shared__ __align__(16) u16 As[BM * 32];
  __shared__ __align__(16) u16 Bs[BN * 32];

  const int tid = threadIdx.x;
  const int w = tid >> 6;
  const int lane = tid & 63;
  const int bm = blockIdx.x * BM;
  const int bn = blockIdx.y * BN;
  const int wr = (BN == 128) ? (w >> 1) : w;
  const int wc = (BN == 128) ? (w & 1) : 0;

  f32x4 acc[FI][4];
#pragma unroll
  for (int i = 0; i < FI; ++i)
#pragma unroll
    for (int j = 0; j < 4; ++j) acc[i][j] = (f32x4)0.f;

  for (int k0 = 0; k0 < K; k0 += 32) {
#pragma unroll
    for (int s = 0; s < 2; ++s) {
      const int inst = w * 2 + s;
      const int row = inst * 16 + (lane >> 2);
      int rg = bm + row;
      if (rg > M - 1) rg = M - 1;
      const int c = (lane & 3) ^ ((row >> 1) & 3);
      gload_lds16(A + (size_t)rg * K + k0 + c * 8, &As[inst * 512]);
    }
    if (BN == 128) {
#pragma unroll
      for (int s = 0; s < 2; ++s) {
        const int inst = w * 2 + s;
        const int row = inst * 16 + (lane >> 2);
        const int c = (lane & 3) ^ ((row >> 1) & 3);
        gload_lds16(Bt + (size_t)(bn + row) * K + k0 + c * 8,
                    &Bs[inst * 512]);
      }
    } else {
      const int inst = w;
      const int row = inst * 16 + (lane >> 2);
      const int c = (lane & 3) ^ ((row >> 1) & 3);
      gload_lds16(Bt + (size_t)(bn + row) * K + k0 + c * 8, &Bs[inst * 512]);
    }
    __syncthreads();

    const int kc = lane >> 4;
    short8 af[FI], bfr[4];
#pragma unroll
    for (int i = 0; i < FI; ++i) {
      const int row = wr * WROWS + i * 16 + (lane & 15);
      const int ch = kc ^ ((row >> 1) & 3);
      af[i] = *reinterpret_cast<const short8*>(&As[row * 32 + ch * 8]);
    }
#pragma unroll
    for (int j = 0; j < 4; ++j) {
      const int row = wc * 64 + j * 16 + (lane & 15);
      const int ch = kc ^ ((row >> 1) & 3);
      bfr[j] = *reinterpret_cast<const short8*>(&Bs[row * 32 + ch * 8]);
    }
#pragma unroll
    for (int i = 0; i < FI; ++i)
#pragma unroll
      for (int j = 0; j < 4; ++j)
        acc[i][j] = __builtin_amdgcn_mfma_f32_16x16x32_bf16(af[i], bfr[j],
                                                            acc[i][j], 0, 0, 0);
    __syncthreads();
  }

  if constexpr (QUANT == 1) {
    // int8 quant epilogue (BN=128, N=256), per-row-per-64col scale
    float bv[4];
#pragma unroll
    for (int j = 0; j < 4; ++j)
      bv[j] = bias[bn + wc * 64 + j * 16 + (lane & 15)];
    const int g = (bn >> 6) + wc;  // 64-col block index 0..3
    u32* zq = (u32*)Cout;
#pragma unroll
    for (int i = 0; i < FI; ++i) {
#pragma unroll
      for (int r = 0; r < 4; ++r) {
        float o[4];
#pragma unroll
        for (int j = 0; j < 4; ++j) o[j] = acc[i][j][r] + bv[j];
        float am = fmaxf(fmaxf(fabsf(o[0]), fabsf(o[1])),
                         fmaxf(fabsf(o[2]), fabsf(o[3])));
#pragma unroll
        for (int mk = 1; mk < 16; mk <<= 1) am = fmaxf(am, __shfl_xor(am, mk));
        const float sinv = am > 0.f ? 127.f / am : 0.f;
        const float scv = am > 0.f ? am / 127.f : 0.f;
        const int q0 = __float2int_rn(o[0] * sinv);
        const int q1 = __float2int_rn(o[1] * sinv);
        const int q2 = __float2int_rn(o[2] * sinv);
        const int q3 = __float2int_rn(o[3] * sinv);
        const u32 dw = (q0 & 0xff) | ((q1 & 0xff) << 8) | ((q2 & 0xff) << 16) |
                       ((q3 & 0xff) << 24);
        const int row = bm + wr * WROWS + i * 16 + (lane >> 4) * 4 + r;
        if (row < M) {
          zq[(size_t)row * 64 + g * 16 + (lane & 15)] = dw;
          if ((lane & 15) == 0) scales[(size_t)row * 4 + g] = scv;
        }
      }
    }
  } else if constexpr (QUANT == 2) {
    // int8 quant epilogue (BN=64, N=64), per-row scale
    float bv[4];
#pragma unroll
    for (int j = 0; j < 4; ++j) bv[j] = bias[j * 16 + (lane & 15)];
    u32* zq = (u32*)Cout;
#pragma unroll
    for (int i = 0; i < FI; ++i) {
#pragma unroll
      for (int r = 0; r < 4; ++r) {
        float o[4];
#pragma unroll
        for (int j = 0; j < 4; ++j) o[j] = acc[i][j][r] + bv[j];
        float am = fmaxf(fmaxf(fabsf(o[0]), fabsf(o[1])),
                         fmaxf(fabsf(o[2]), fabsf(o[3])));
#pragma unroll
        for (int mk = 1; mk < 16; mk <<= 1) am = fmaxf(am, __shfl_xor(am, mk));
        const float sinv = am > 0.f ? 127.f / am : 0.f;
        const float scv = am > 0.f ? am / 127.f : 0.f;
        const int q0 = __float2int_rn(o[0] * sinv);
        const int q1 = __float2int_rn(o[1] * sinv);
        const int q2 = __float2int_rn(o[2] * sinv);
        const int q3 = __float2int_rn(o[3] * sinv);
        const u32 dw = (q0 & 0xff) | ((q1 & 0xff) << 8) | ((q2 & 0xff) << 16) |
                       ((q3 & 0xff) << 24);
        const int row = bm + wr * WROWS + i * 16 + (lane >> 4) * 4 + r;
        if (row < M) {
          zq[(size_t)row * 16 + (lane & 15)] = dw;
          if ((lane & 15) == 0) scales[row] = scv;
        }
      }
    }
  } else {
    u16* C = (u16*)Cout;
#pragma unroll
    for (int i = 0; i < FI; ++i) {
#pragma unroll
      for (int j = 0; j < 4; ++j) {
        const int col = bn + wc * 64 + j * 16 + (lane & 15);
        const float bv = bias[col];
#pragma unroll
        for (int r = 0; r < 4; ++r) {
          const int row = bm + wr * WROWS + i * 16 + (lane >> 4) * 4 + r;
          if (row < M) {
            float o = acc[i][j][r] + bv;
            if (RELU_OUT) o = fmaxf(o, 0.f);
            C[(size_t)row * N + col] = f2bf(o);
          }
        }
      }
    }
  }
}

// ---------------------------------------------------------------------------
// conversions: both inputs in one launch
// ---------------------------------------------------------------------------
__global__ __launch_bounds__(256) void cvt_all(const float4* __restrict__ xa,
                                               ushort4* __restrict__ xab,
                                               const float4* __restrict__ xb,
                                               ushort4* __restrict__ xbb) {
  const int i = blockIdx.x * 256 + threadIdx.x;
  const int na4 = NA * 64;       // NA*256/4
  const int nb4 = NB * 32;       // NB*128/4
  if (i < na4) {
    const float4 v = xa[i];
    ushort4 o;
    o.x = f2bf(v.x); o.y = f2bf(v.y); o.z = f2bf(v.z); o.w = f2bf(v.w);
    xab[i] = o;
  } else if (i < na4 + nb4) {
    const int t = i - na4;
    const float4 v = xb[t];
    ushort4 o;
    o.x = f2bf(v.x); o.y = f2bf(v.y); o.z = f2bf(v.z); o.w = f2bf(v.w);
    xbb[t] = o;
  }
}

// All 4 weight transposes in one launch. W2t additionally applies the
// int8 storage permutation: W2t[n*256+p] = W2[f(p)*64+n],
// f(p) = 64*(p>>6) + 16*(p&3) + ((p>>2)&15).
__global__ __launch_bounds__(256) void wt_all(
    const float* __restrict__ W1a, const float* __restrict__ W1b,
    const float* __restrict__ Wf, const float* __restrict__ W2,
    u16* __restrict__ W1at, u16* __restrict__ W1bt, u16* __restrict__ Wft,
    u16* __restrict__ W2t) {
  const int i = blockIdx.x * 256 + threadIdx.x;
  if (i < 65536) {                       // W1a [256,256] -> [256,256]
    const int n = i >> 8, k = i & 255;
    W1at[i] = f2bf(W1a[k * 256 + n]);
  } else if (i < 98304) {                // W1b [128,256] -> [256,128]
    const int t = i - 65536;
    const int n = t >> 7, k = t & 127;
    W1bt[t] = f2bf(W1b[k * 256 + n]);
  } else if (i < 163840) {               // Wf [256,256] -> [256,256]
    const int t = i - 98304;
    const int n = t >> 8, k = t & 255;
    Wft[t] = f2bf(Wf[k * 256 + n]);
  } else if (i < 180224) {               // W2 [256,64] -> [64,256] permuted
    const int t = i - 163840;
    const int n = t >> 8, p = t & 255;
    const int f = ((p >> 6) << 6) + ((p & 3) << 4) + ((p >> 2) & 15);
    W2t[t] = f2bf(W2[f * 64 + n]);
  }
}

// ---------------------------------------------------------------------------
// Bucket radix partition + per-bucket (row, col-chunk) counting sort.
// ---------------------------------------------------------------------------
__global__ __launch_bounds__(256) void p1_hist(const int* __restrict__ rows,
                                               int* __restrict__ cnt) {
  __shared__ int h[NBUCK];
  const int tid = threadIdx.x;
  for (int i = tid; i < NBUCK; i += 256) h[i] = 0;
  __syncthreads();
  const int s = blockIdx.x * CHUNK;
  const int e = s + CHUNK;
  for (int i = s + tid; i < e; i += 256) atomicAdd(&h[rows[i] >> 6], 1);
  __syncthreads();
  for (int i = tid; i < NBUCK; i += 256) cnt[i * PBLK + blockIdx.x] = h[i];
}

__global__ __launch_bounds__(256) void s1_scan_blocks(int* __restrict__ cnt,
                                                      int* __restrict__ btot) {
  __shared__ int lds[256];
  const int bu = blockIdx.x;
  const int t = threadIdx.x;
  const int v = cnt[bu * PBLK + t];
  lds[t] = v;
  __syncthreads();
#pragma unroll
  for (int off = 1; off < 256; off <<= 1) {
    const int x = (t >= off) ? lds[t - off] : 0;
    __syncthreads();
    lds[t] += x;
    __syncthreads();
  }
  cnt[bu * PBLK + t] = lds[t] - v;
  if (t == 255) btot[bu] = lds[255];
}

__global__ __launch_bounds__(1024) void s2_scan_buckets(
    const int* __restrict__ btot, int* __restrict__ bstart) {
  __shared__ int lds[1024];
  __shared__ int carry;
  const int t = threadIdx.x;
  if (t == 0) carry = 0;
  __syncthreads();
  for (int base = 0; base < NBUCK; base += 1024) {
    const int i = base + t;
    const int v = (i < NBUCK) ? btot[i] : 0;
    lds[t] = v;
    __syncthreads();
#pragma unroll
    for (int off = 1; off < 1024; off <<= 1) {
      const int x = (t >= off) ? lds[t - off] : 0;
      __syncthreads();
      lds[t] += x;
      __syncthreads();
    }
    const int excl = lds[t] - v;
    const int c = carry;
    if (i < NBUCK) bstart[i] = c + excl;
    __syncthreads();
    if (t == 0) carry = c + lds[1023];
    __syncthreads();
  }
  if (t == 0) bstart[NBUCK] = NE;
}

__global__ __launch_bounds__(256) void p3_scatter(
    const int* __restrict__ rows, const int* __restrict__ cols,
    const float* __restrict__ vals, const int* __restrict__ cnt,
    const int* __restrict__ bstart, int2* __restrict__ edges) {
  __shared__ int lcur[NBUCK];
  const int tid = threadIdx.x;
  const int blk = blockIdx.x;
  for (int bu = tid; bu < NBUCK; bu += 256)
    lcur[bu] = bstart[bu] + cnt[bu * PBLK + blk];
  __syncthreads();
  const int s = blk * CHUNK;
  const int e = s + CHUNK;
  for (int i = s + tid; i < e; i += 256) {
    const int r = rows[i];
    const int bu = r >> 6;
    const int lr = r & 63;
    const int pos = atomicAdd(&lcur[bu], 1);
    edges[pos] = make_int2(cols[i] | (lr << 17), __float_as_int(vals[i]));
  }
}

// Per-bucket counting sort by (row, col>>13) -> edges2 grouped so each row's
// edges walk zq in 8192-col chunks (2.1MB L2-resident slices). 1024 bins.
__global__ __launch_bounds__(1024) void sort_bucket(
    const int* __restrict__ bstart, const int2* __restrict__ edges,
    int2* __restrict__ edges2, int* __restrict__ rptr) {
  __shared__ int hist[SBINS];
  __shared__ int sc[SBINS];
  __shared__ int cur[SBINS];
  const int bu = blockIdx.x;
  const int t = threadIdx.x;
  const int s = bstart[bu], e = bstart[bu + 1];
  hist[t] = 0;
  __syncthreads();
  for (int i = s + t; i < e; i += 1024) {
    const int x = edges[i].x;
    const int k = (((x >> 17) & 63) << 4) | ((x & 0x1FFFF) >> SCHUNK_SHIFT);
    atomicAdd(&hist[k], 1);
  }
  __syncthreads();
  const int hv = hist[t];
  sc[t] = hv;
  __syncthreads();
#pragma unroll
  for (int off = 1; off < SBINS; off <<= 1) {
    const int x = (t >= off) ? sc[t - off] : 0;
    __syncthreads();
    sc[t] += x;
    __syncthreads();
  }
  const int excl = sc[t] - hv;
  cur[t] = s + excl;
  if ((t & 15) == 0) {
    const int grow = bu * RPB + (t >> 4);
    if (grow < NN) rptr[grow] = s + excl;
  }
  if (bu == 0 && t == 0) rptr[NN] = NE;
  __syncthreads();
  for (int i = s + t; i < e; i += 1024) {
    const int2 ed = edges[i];
    const int k =
        (((ed.x >> 17) & 63) << 4) | ((ed.x & 0x1FFFF) >> SCHUNK_SHIFT);
    const int pos = atomicAdd(&cur[k], 1);
    edges2[pos] = make_int2(ed.x & 0x1FFFF, ed.y);
  }
}

// ---------------------------------------------------------------------------
// CSR SpMM width 256, int8 input (per-row-per-64col scale), relu+bf16 out.
// One wave/row, lane = 1 dword (4 features). unroll 8.
// ---------------------------------------------------------------------------
__global__ __launch_bounds__(256) void spmm256_q8(
    const int* __restrict__ ptr, const int2* __restrict__ edges,
    const u32* __restrict__ Zq, const float* __restrict__ scales,
    u16* __restrict__ Yb) {
  const int wid = (int)((blockIdx.x * (size_t)256 + threadIdx.x) >> 6);
  const int lane = threadIdx.x & 63;
  if (wid >= NN) return;
  const int s = ptr[wid], e = ptr[wid + 1];
  const int gsel = lane >> 4;
  float a0 = 0.f, a1 = 0.f, a2 = 0.f, a3 = 0.f;
  int j = s;
  for (; j + 7 < e; j += 8) {
    int2 ed[8];
#pragma unroll
    for (int q = 0; q < 8; ++q) ed[q] = edges[j + q];
    u32 dw[8];
    float sc[8];
#pragma unroll
    for (int q = 0; q < 8; ++q) {
      dw[q] = Zq[(size_t)ed[q].x * 64 + lane];
      sc[q] = scales[(size_t)ed[q].x * 4 + gsel];
    }
#pragma unroll
    for (int q = 0; q < 8; ++q) {
      const float vs = __int_as_float(ed[q].y) * sc[q];
      a0 += vs * i8f(dw[q], 0);
      a1 += vs * i8f(dw[q], 1);
      a2 += vs * i8f(dw[q], 2);
      a3 += vs * i8f(dw[q], 3);
    }
  }
  for (; j < e; ++j) {
    const int2 e0 = edges[j];
    const u32 dw = Zq[(size_t)e0.x * 64 + lane];
    const float vs =
        __int_as_float(e0.y) * scales[(size_t)e0.x * 4 + gsel];
    a0 += vs * i8f(dw, 0);
    a1 += vs * i8f(dw, 1);
    a2 += vs * i8f(dw, 2);
    a3 += vs * i8f(dw, 3);
  }
  ushort4 o;  // relu + bf16 (output stays in permuted feature order)
  o.x = f2bf(fmaxf(a0, 0.f));
  o.y = f2bf(fmaxf(a1, 0.f));
  o.z = f2bf(fmaxf(a2, 0.f));
  o.w = f2bf(fmaxf(a3, 0.f));
  reinterpret_cast<ushort4*>(Yb + (size_t)wid * 256)[lane] = o;
}

// ---------------------------------------------------------------------------
// CSR SpMM width 64, int8 input (per-row scale), fp32 out (canonical order).
// One wave/row; lane f reads byte f>>4 of dword f&15. unroll 8.
// ---------------------------------------------------------------------------
__global__ __launch_bounds__(256) void spmm64_q8(
    const int* __restrict__ ptr, const int2* __restrict__ edges,
    const u32* __restrict__ Z2q, const float* __restrict__ zsc2,
    float* __restrict__ Y) {
  const int wid = (int)((blockIdx.x * (size_t)256 + threadIdx.x) >> 6);
  const int lane = threadIdx.x & 63;
  if (wid >= NN) return;
  const int s = ptr[wid], e = ptr[wid + 1];
  const int dwi = lane & 15;
  const int byi = lane >> 4;
  float acc = 0.f;
  int j = s;
  for (; j + 7 < e; j += 8) {
    int2 ed[8];
#pragma unroll
    for (int q = 0; q < 8; ++q) ed[q] = edges[j + q];
    u32 dw[8];
    float sc[8];
#pragma unroll
    for (int q = 0; q < 8; ++q) {
      dw[q] = Z2q[(size_t)ed[q].x * 16 + dwi];
      sc[q] = zsc2[ed[q].x];
    }
#pragma unroll
    for (int q = 0; q < 8; ++q)
      acc += __int_as_float(ed[q].y) * sc[q] * i8f(dw[q], byi);
  }
  for (; j < e; ++j) {
    const int2 e0 = edges[j];
    const u32 dw = Z2q[(size_t)e0.x * 16 + dwi];
    acc += __int_as_float(e0.y) * zsc2[e0.x] * i8f(dw, byi);
  }
  Y[(size_t)wid * 64 + lane] = acc;
}

extern "C" void kernel_launch(void* const* d_in, const int* in_sizes, int n_in,
                              void* d_out, int out_size, void* d_ws,
                              size_t ws_size, hipStream_t stream) {
  const float* x_a  = (const float*)d_in[0];
  const float* x_b  = (const float*)d_in[1];
  const int*   rows = (const int*)d_in[2];
  const int*   cols = (const int*)d_in[3];
  const float* vals = (const float*)d_in[4];
  const float* W1a  = (const float*)d_in[5];
  const float* b1a  = (const float*)d_in[6];
  const float* W1b  = (const float*)d_in[7];
  const float* b1b  = (const float*)d_in[8];
  const float* Wf   = (const float*)d_in[9];
  const float* bf   = (const float*)d_in[10];
  const float* W2   = (const float*)d_in[11];
  const float* b2   = (const float*)d_in[12];
  float* out = (float*)d_out;

  // workspace (~155 MB); edges2 aliases xab/xbb (dead after gemm1/2)
  char* p = (char*)d_ws;
  u16* h    = (u16*)p;  p += (size_t)NN * NHID * 2;   // h, later s1b
  u32* zq   = (u32*)p;  p += (size_t)NN * 64 * 4;     // 25.6MB int8 z
  float* zscale = (float*)p; p += (size_t)NN * 4 * 4; // 1.6MB
  u32* z2q  = (u32*)p;  p += (size_t)NN * 16 * 4;     // 6.4MB int8 z2
  float* zsc2 = (float*)p; p += (size_t)NN * 4;       // 0.4MB
  u16* xab  = (u16*)p;  p += (size_t)NA * 256 * 2;    // \ edges2 aliases
  u16* xbb  = (u16*)p;  p += (size_t)NB * 128 * 2;    // /  (40.9MB >= 25.6MB)
  u16* W1at = (u16*)p;  p += 256 * 256 * 2;
  u16* W1bt = (u16*)p;  p += 256 * 128 * 2;
  u16* Wft  = (u16*)p;  p += 256 * 256 * 2;
  u16* W2t  = (u16*)p;  p += 64 * 256 * 2;
  int2* edges = (int2*)p; p += (size_t)NE * 8;
  int* cnt    = (int*)p;  p += (size_t)NBUCK * PBLK * 4;
  int* btot   = (int*)p;  p += (size_t)((NBUCK + 3) & ~3) * 4;
  int* bstart = (int*)p;  p += (size_t)((NBUCK + 4) & ~3) * 4;
  int* rptr   = (int*)p;  p += (size_t)(NN + 4) * 4;
  u16* s1b = h;
  int2* edges2 = (int2*)xab;

  // --- conversions ---
  cvt_all<<<(NA * 64 + NB * 32 + 255) / 256, 256, 0, stream>>>(
      (const float4*)x_a, (ushort4*)xab, (const float4*)x_b, (ushort4*)xbb);
  wt_all<<<704, 256, 0, stream>>>(W1a, W1b, Wf, W2, W1at, W1bt, Wft, W2t);

  // --- dense pipeline through gemm3 (xab/xbb live here) ---
  gemm_mfma<128, 1, 0><<<dim3((NA + 127) / 128, 2), 256, 0, stream>>>(
      xab, W1at, b1a, h, nullptr, NA, NHID, 256);
  gemm_mfma<128, 1, 0><<<dim3((NB + 127) / 128, 2), 256, 0, stream>>>(
      xbb, W1bt, b1b, h + (size_t)NA * NHID, nullptr, NB, NHID, 128);
  // zq = int8(h @ Wf + bf), per-64col scales
  gemm_mfma<128, 0, 1><<<dim3((NN + 127) / 128, 2), 256, 0, stream>>>(
      h, Wft, bf, zq, zscale, NN, NHID, 256);

  // --- CSR build (xab/xbb now dead; edges2 reuses their space) ---
  p1_hist<<<PBLK, 256, 0, stream>>>(rows, cnt);
  s1_scan_blocks<<<NBUCK, 256, 0, stream>>>(cnt, btot);
  s2_scan_buckets<<<1, 1024, 0, stream>>>(btot, bstart);
  p3_scatter<<<PBLK, 256, 0, stream>>>(rows, cols, vals, cnt, bstart, edges);
  sort_bucket<<<NBUCK, 1024, 0, stream>>>(bstart, edges, edges2, rptr);

  // --- sparse + tail ---
  // s1b = bf16(relu(spmm(zq)))   (permuted feature order; W2t compensates)
  spmm256_q8<<<(NN * 64 + 255) / 256, 256, 0, stream>>>(rptr, edges2, zq,
                                                        zscale, s1b);
  // z2q = int8(s1b @ W2t^T + b2), per-row scale
  gemm_mfma<64, 0, 2><<<dim3((NN + 127) / 128, 1), 256, 0, stream>>>(
      s1b, W2t, b2, z2q, zsc2, NN, NOUT, 256);
  // out = spmm(z2q)  (canonical feature order restored per-lane)
  spmm64_q8<<<(NN * 64 + 255) / 256, 256, 0, stream>>>(rptr, edges2, z2q,
                                                       zsc2, out);
}

// Round 11
// 491.932 us; speedup vs baseline: 1.0408x; 1.0408x over previous
//
#include <hip/hip_runtime.h>

#define NN 100000
#define NE 3200000
#define NA 60000
#define NB 40000
#define NHID 256
#define NOUT 64

#define RPB 64                    // rows per bucket
#define NBUCK 1563                // ceil(NN/64)
#define PBLK 256                  // partition blocks
#define CHUNK 12500               // NE / PBLK (exact)

// prep-kernel block ranges
#define CVT_BLKS 20000            // (NA*64 + NB*32) / 256
#define WT_BLKS 704               // 180224 / 256
// gemm12_s1 block ranges
#define G1_BLKS 938               // 469 * 2
#define G2_BLKS 626               // 313 * 2
// gemm3_s2
#define G3_BLKS 1564              // 782 * 2

typedef unsigned short u16;
typedef unsigned int u32;
typedef __attribute__((ext_vector_type(8))) short short8;
typedef __attribute__((ext_vector_type(4))) float f32x4;

__device__ __forceinline__ float bf2f(u16 u) {
  return __uint_as_float(((u32)u) << 16);
}
__device__ __forceinline__ u16 f2bf(float f) {
  u32 u = __float_as_uint(f);
  u32 r = (u + 0x7fffu + ((u >> 16) & 1u)) >> 16;  // RNE
  return (u16)r;
}
// sign-extend byte b of dw to float
__device__ __forceinline__ float i8f(u32 dw, int b) {
  return (float)((int)(dw << (24 - 8 * b)) >> 24);
}

__device__ __forceinline__ void gload_lds16(const void* gsrc, void* ldst) {
  __builtin_amdgcn_global_load_lds(
      (const __attribute__((address_space(1))) void*)gsrc,
      (__attribute__((address_space(3))) void*)ldst, 16, 0, 0);
}

// ---------------------------------------------------------------------------
// bf16 MFMA GEMM body (device fn; As/Bs are caller LDS: 128*32 / BN*32 u16).
// QUANT=0: bf16 out (opt relu).
// QUANT=1 (BN=128, N=256): int8 out, per-row-per-64col scale, lane-major pack.
// QUANT=2 (BN=64, N=64): int8 out, per-row scale, lane-major pack.
// ---------------------------------------------------------------------------
template <int BN, int RELU_OUT, int QUANT>
__device__ __forceinline__ void gemm_body(
    int bx, int by, const u16* __restrict__ A, const u16* __restrict__ Bt,
    const float* __restrict__ bias, void* __restrict__ Cout,
    float* __restrict__ scales, int M, int N, int K, u16* As, u16* Bs) {
  constexpr int FI = (BN == 128) ? 4 : 2;
  constexpr int WROWS = FI * 16;

  const int tid = threadIdx.x;
  const int w = tid >> 6;
  const int lane = tid & 63;
  const int bm = bx * 128;
  const int bn = by * BN;
  const int wr = (BN == 128) ? (w >> 1) : w;
  const int wc = (BN == 128) ? (w & 1) : 0;

  f32x4 acc[FI][4];
#pragma unroll
  for (int i = 0; i < FI; ++i)
#pragma unroll
    for (int j = 0; j < 4; ++j) acc[i][j] = (f32x4)0.f;

  for (int k0 = 0; k0 < K; k0 += 32) {
#pragma unroll
    for (int s = 0; s < 2; ++s) {
      const int inst = w * 2 + s;
      const int row = inst * 16 + (lane >> 2);
      int rg = bm + row;
      if (rg > M - 1) rg = M - 1;
      const int c = (lane & 3) ^ ((row >> 1) & 3);
      gload_lds16(A + (size_t)rg * K + k0 + c * 8, &As[inst * 512]);
    }
    if (BN == 128) {
#pragma unroll
      for (int s = 0; s < 2; ++s) {
        const int inst = w * 2 + s;
        const int row = inst * 16 + (lane >> 2);
        const int c = (lane & 3) ^ ((row >> 1) & 3);
        gload_lds16(Bt + (size_t)(bn + row) * K + k0 + c * 8,
                    &Bs[inst * 512]);
      }
    } else {
      const int inst = w;
      const int row = inst * 16 + (lane >> 2);
      const int c = (lane & 3) ^ ((row >> 1) & 3);
      gload_lds16(Bt + (size_t)(bn + row) * K + k0 + c * 8, &Bs[inst * 512]);
    }
    __syncthreads();

    const int kc = lane >> 4;
    short8 af[FI], bfr[4];
#pragma unroll
    for (int i = 0; i < FI; ++i) {
      const int row = wr * WROWS + i * 16 + (lane & 15);
      const int ch = kc ^ ((row >> 1) & 3);
      af[i] = *reinterpret_cast<const short8*>(&As[row * 32 + ch * 8]);
    }
#pragma unroll
    for (int j = 0; j < 4; ++j) {
      const int row = wc * 64 + j * 16 + (lane & 15);
      const int ch = kc ^ ((row >> 1) & 3);
      bfr[j] = *reinterpret_cast<const short8*>(&Bs[row * 32 + ch * 8]);
    }
#pragma unroll
    for (int i = 0; i < FI; ++i)
#pragma unroll
      for (int j = 0; j < 4; ++j)
        acc[i][j] = __builtin_amdgcn_mfma_f32_16x16x32_bf16(af[i], bfr[j],
                                                            acc[i][j], 0, 0, 0);
    __syncthreads();
  }

  if constexpr (QUANT == 1) {
    float bv[4];
#pragma unroll
    for (int j = 0; j < 4; ++j)
      bv[j] = bias[bn + wc * 64 + j * 16 + (lane & 15)];
    const int g = (bn >> 6) + wc;  // 64-col block index 0..3
    u32* zq = (u32*)Cout;
#pragma unroll
    for (int i = 0; i < FI; ++i) {
#pragma unroll
      for (int r = 0; r < 4; ++r) {
        float o[4];
#pragma unroll
        for (int j = 0; j < 4; ++j) o[j] = acc[i][j][r] + bv[j];
        float am = fmaxf(fmaxf(fabsf(o[0]), fabsf(o[1])),
                         fmaxf(fabsf(o[2]), fabsf(o[3])));
#pragma unroll
        for (int mk = 1; mk < 16; mk <<= 1) am = fmaxf(am, __shfl_xor(am, mk));
        const float sinv = am > 0.f ? 127.f / am : 0.f;
        const float scv = am > 0.f ? am / 127.f : 0.f;
        const int q0 = __float2int_rn(o[0] * sinv);
        const int q1 = __float2int_rn(o[1] * sinv);
        const int q2 = __float2int_rn(o[2] * sinv);
        const int q3 = __float2int_rn(o[3] * sinv);
        const u32 dw = (q0 & 0xff) | ((q1 & 0xff) << 8) | ((q2 & 0xff) << 16) |
                       ((q3 & 0xff) << 24);
        const int row = bm + wr * WROWS + i * 16 + (lane >> 4) * 4 + r;
        if (row < M) {
          zq[(size_t)row * 64 + g * 16 + (lane & 15)] = dw;
          if ((lane & 15) == 0) scales[(size_t)row * 4 + g] = scv;
        }
      }
    }
  } else if constexpr (QUANT == 2) {
    float bv[4];
#pragma unroll
    for (int j = 0; j < 4; ++j) bv[j] = bias[j * 16 + (lane & 15)];
    u32* zq = (u32*)Cout;
#pragma unroll
    for (int i = 0; i < FI; ++i) {
#pragma unroll
      for (int r = 0; r < 4; ++r) {
        float o[4];
#pragma unroll
        for (int j = 0; j < 4; ++j) o[j] = acc[i][j][r] + bv[j];
        float am = fmaxf(fmaxf(fabsf(o[0]), fabsf(o[1])),
                         fmaxf(fabsf(o[2]), fabsf(o[3])));
#pragma unroll
        for (int mk = 1; mk < 16; mk <<= 1) am = fmaxf(am, __shfl_xor(am, mk));
        const float sinv = am > 0.f ? 127.f / am : 0.f;
        const float scv = am > 0.f ? am / 127.f : 0.f;
        const int q0 = __float2int_rn(o[0] * sinv);
        const int q1 = __float2int_rn(o[1] * sinv);
        const int q2 = __float2int_rn(o[2] * sinv);
        const int q3 = __float2int_rn(o[3] * sinv);
        const u32 dw = (q0 & 0xff) | ((q1 & 0xff) << 8) | ((q2 & 0xff) << 16) |
                       ((q3 & 0xff) << 24);
        const int row = bm + wr * WROWS + i * 16 + (lane >> 4) * 4 + r;
        if (row < M) {
          zq[(size_t)row * 16 + (lane & 15)] = dw;
          if ((lane & 15) == 0) scales[row] = scv;
        }
      }
    }
  } else {
    u16* C = (u16*)Cout;
#pragma unroll
    for (int i = 0; i < FI; ++i) {
#pragma unroll
      for (int j = 0; j < 4; ++j) {
        const int col = bn + wc * 64 + j * 16 + (lane & 15);
        const float bv = bias[col];
#pragma unroll
        for (int r = 0; r < 4; ++r) {
          const int row = bm + wr * WROWS + i * 16 + (lane >> 4) * 4 + r;
          if (row < M) {
            float o = acc[i][j][r] + bv;
            if (RELU_OUT) o = fmaxf(o, 0.f);
            C[(size_t)row * N + col] = f2bf(o);
          }
        }
      }
    }
  }
}

// Standalone GEMM wrapper (used for gemm4)
template <int BN, int RELU_OUT, int QUANT>
__global__ __launch_bounds__(256) void gemm_mfma(
    const u16* __restrict__ A, const u16* __restrict__ Bt,
    const float* __restrict__ bias, void* __restrict__ Cout,
    float* __restrict__ scales, int M, int N, int K) {
  __shared__ __align__(16) u16 As[128 * 32];
  __shared__ __align__(16) u16 Bs[BN * 32];
  gemm_body<BN, RELU_OUT, QUANT>(blockIdx.x, blockIdx.y, A, Bt, bias, Cout,
                                 scales, M, N, K, As, Bs);
}

// ---------------------------------------------------------------------------
// L1 prep: cvt_a | cvt_b | weight transposes | p1 bucket histogram
// ---------------------------------------------------------------------------
__global__ __launch_bounds__(256) void prep(
    const float4* __restrict__ xa, ushort4* __restrict__ xab4,
    const float4* __restrict__ xb, ushort4* __restrict__ xbb4,
    const float* __restrict__ W1a, const float* __restrict__ W1b,
    const float* __restrict__ Wf, const float* __restrict__ W2,
    u16* __restrict__ W1at, u16* __restrict__ W1bt, u16* __restrict__ Wft,
    u16* __restrict__ W2t, const int* __restrict__ rows,
    int* __restrict__ cnt) {
  __shared__ int hsh[NBUCK];
  const int b = blockIdx.x;
  const int tid = threadIdx.x;
  if (b < CVT_BLKS) {
    const int i = b * 256 + tid;
    const int na4 = NA * 64;
    if (i < na4) {
      const float4 v = xa[i];
      ushort4 o;
      o.x = f2bf(v.x); o.y = f2bf(v.y); o.z = f2bf(v.z); o.w = f2bf(v.w);
      xab4[i] = o;
    } else {
      const int t = i - na4;  // < NB*32 guaranteed (exact block count)
      const float4 v = xb[t];
      ushort4 o;
      o.x = f2bf(v.x); o.y = f2bf(v.y); o.z = f2bf(v.z); o.w = f2bf(v.w);
      xbb4[t] = o;
    }
  } else if (b < CVT_BLKS + WT_BLKS) {
    const int i = (b - CVT_BLKS) * 256 + tid;
    if (i < 65536) {                       // W1a [256,256] -> [256,256]
      const int n = i >> 8, k = i & 255;
      W1at[i] = f2bf(W1a[k * 256 + n]);
    } else if (i < 98304) {                // W1b [128,256] -> [256,128]
      const int t = i - 65536;
      const int n = t >> 7, k = t & 127;
      W1bt[t] = f2bf(W1b[k * 256 + n]);
    } else if (i < 163840) {               // Wf [256,256] -> [256,256]
      const int t = i - 98304;
      const int n = t >> 8, k = t & 255;
      Wft[t] = f2bf(Wf[k * 256 + n]);
    } else if (i < 180224) {               // W2 [256,64] -> [64,256] permuted
      const int t = i - 163840;
      const int n = t >> 8, p = t & 255;
      const int f = ((p >> 6) << 6) + ((p & 3) << 4) + ((p >> 2) & 15);
      W2t[t] = f2bf(W2[f * 64 + n]);
    }
  } else {
    // p1 histogram, partition block blk in [0, PBLK)
    const int blk = b - (CVT_BLKS + WT_BLKS);
    for (int i = tid; i < NBUCK; i += 256) hsh[i] = 0;
    __syncthreads();
    const int s = blk * CHUNK;
    const int e = s + CHUNK;
    for (int i = s + tid; i < e; i += 256) atomicAdd(&hsh[rows[i] >> 6], 1);
    __syncthreads();
    for (int i = tid; i < NBUCK; i += 256) cnt[i * PBLK + blk] = hsh[i];
  }
}

// ---------------------------------------------------------------------------
// L2: gemm1 | gemm2 | s1 per-bucket scan of block counts
// ---------------------------------------------------------------------------
__global__ __launch_bounds__(256) void gemm12_s1(
    const u16* __restrict__ xab, const u16* __restrict__ W1at,
    const float* __restrict__ b1a, const u16* __restrict__ xbb,
    const u16* __restrict__ W1bt, const float* __restrict__ b1b,
    u16* __restrict__ h, int* __restrict__ cnt, int* __restrict__ btot) {
  __shared__ __align__(16) u16 As[128 * 32];
  __shared__ __align__(16) u16 Bs[128 * 32];
  const int b = blockIdx.x;
  if (b < G1_BLKS) {
    gemm_body<128, 1, 0>(b % 469, b / 469, xab, W1at, b1a, h, nullptr, NA,
                         NHID, 256, As, Bs);
  } else if (b < G1_BLKS + G2_BLKS) {
    const int t = b - G1_BLKS;
    gemm_body<128, 1, 0>(t % 313, t / 313, xbb, W1bt, b1b,
                         h + (size_t)NA * NHID, nullptr, NB, NHID, 128, As,
                         Bs);
  } else {
    // s1: exclusive scan of cnt[bu][0..255] -> in place, total -> btot[bu]
    int* lds = (int*)As;
    const int bu = b - (G1_BLKS + G2_BLKS);
    const int t = threadIdx.x;
    const int v = cnt[bu * PBLK + t];
    lds[t] = v;
    __syncthreads();
#pragma unroll
    for (int off = 1; off < 256; off <<= 1) {
      const int x = (t >= off) ? lds[t - off] : 0;
      __syncthreads();
      lds[t] += x;
      __syncthreads();
    }
    cnt[bu * PBLK + t] = lds[t] - v;
    if (t == 255) btot[bu] = lds[255];
  }
}

// ---------------------------------------------------------------------------
// L3: gemm3 (int8 quant out) | s2 scan of bucket totals
// ---------------------------------------------------------------------------
__global__ __launch_bounds__(256) void gemm3_s2(
    const u16* __restrict__ h, const u16* __restrict__ Wft,
    const float* __restrict__ bfv, u32* __restrict__ zq,
    float* __restrict__ zscale, const int* __restrict__ btot,
    int* __restrict__ bstart) {
  __shared__ __align__(16) u16 As[128 * 32];
  __shared__ __align__(16) u16 Bs[128 * 32];
  const int b = blockIdx.x;
  if (b < G3_BLKS) {
    gemm_body<128, 0, 1>(b % 782, b / 782, h, Wft, bfv, zq, zscale, NN, NHID,
                         256, As, Bs);
  } else {
    // s2: exclusive scan of btot[0..NBUCK) -> bstart, 256-wide with carry
    int* lds = (int*)As;
    const int t = threadIdx.x;
    int carry = 0;
    for (int base = 0; base < NBUCK; base += 256) {
      const int i = base + t;
      const int v = (i < NBUCK) ? btot[i] : 0;
      lds[t] = v;
      __syncthreads();
#pragma unroll
      for (int off = 1; off < 256; off <<= 1) {
        const int x = (t >= off) ? lds[t - off] : 0;
        __syncthreads();
        lds[t] += x;
        __syncthreads();
      }
      const int excl = lds[t] - v;
      const int tot = lds[255];
      if (i < NBUCK) bstart[i] = carry + excl;
      __syncthreads();
      carry += tot;
    }
    if (t == 0) bstart[NBUCK] = NE;
  }
}

// ---------------------------------------------------------------------------
// p3 scatter into bucket segments (deterministic offsets, LDS cursors)
// ---------------------------------------------------------------------------
__global__ __launch_bounds__(256) void p3_scatter(
    const int* __restrict__ rows, const int* __restrict__ cols,
    const float* __restrict__ vals, const int* __restrict__ cnt,
    const int* __restrict__ bstart, int2* __restrict__ edges) {
  __shared__ int lcur[NBUCK];
  const int tid = threadIdx.x;
  const int blk = blockIdx.x;
  for (int bu = tid; bu < NBUCK; bu += 256)
    lcur[bu] = bstart[bu] + cnt[bu * PBLK + blk];
  __syncthreads();
  const int s = blk * CHUNK;
  const int e = s + CHUNK;
  for (int i = s + tid; i < e; i += 256) {
    const int r = rows[i];
    const int bu = r >> 6;
    const int lr = r & 63;
    const int pos = atomicAdd(&lcur[bu], 1);
    edges[pos] = make_int2(cols[i] | (lr << 17), __float_as_int(vals[i]));
  }
}

// Per-bucket counting sort -> row-sorted edges2 + rptr. One block per bucket.
__global__ __launch_bounds__(256) void sort_bucket(
    const int* __restrict__ bstart, const int2* __restrict__ edges,
    int2* __restrict__ edges2, int* __restrict__ rptr) {
  __shared__ int hist[RPB];
  __shared__ int sc[RPB];
  __shared__ int cur[RPB];
  const int bu = blockIdx.x;
  const int t = threadIdx.x;
  const int s = bstart[bu], e = bstart[bu + 1];
  if (t < RPB) hist[t] = 0;
  __syncthreads();
  for (int i = s + t; i < e; i += 256)
    atomicAdd(&hist[(edges[i].x >> 17) & 63], 1);
  __syncthreads();
  const int hv = (t < RPB) ? hist[t] : 0;
  if (t < RPB) sc[t] = hv;
  __syncthreads();
#pragma unroll
  for (int off = 1; off < RPB; off <<= 1) {
    const int x = (t >= off && t < RPB) ? sc[t - off] : 0;
    __syncthreads();
    if (t < RPB) sc[t] += x;
    __syncthreads();
  }
  if (t < RPB) {
    const int base = s + sc[t] - hv;
    cur[t] = base;
    const int grow = bu * RPB + t;
    if (grow < NN) rptr[grow] = base;
  }
  if (bu == 0 && t == 0) rptr[NN] = NE;
  __syncthreads();
  for (int i = s + t; i < e; i += 256) {
    const int2 ed = edges[i];
    const int lr = (ed.x >> 17) & 63;
    const int pos = atomicAdd(&cur[lr], 1);
    edges2[pos] = make_int2(ed.x & 0x1FFFF, ed.y);
  }
}

// ---------------------------------------------------------------------------
// CSR SpMM width 256, int8 input (per-row-per-64col scale), relu+bf16 out.
// One wave/row, lane = 1 dword (4 features). unroll 8.
// ---------------------------------------------------------------------------
__global__ __launch_bounds__(256) void spmm256_q8(
    const int* __restrict__ ptr, const int2* __restrict__ edges,
    const u32* __restrict__ Zq, const float* __restrict__ scales,
    u16* __restrict__ Yb) {
  const int wid = (int)((blockIdx.x * (size_t)256 + threadIdx.x) >> 6);
  const int lane = threadIdx.x & 63;
  if (wid >= NN) return;
  const int s = ptr[wid], e = ptr[wid + 1];
  const int gsel = lane >> 4;
  float a0 = 0.f, a1 = 0.f, a2 = 0.f, a3 = 0.f;
  int j = s;
  for (; j + 7 < e; j += 8) {
    int2 ed[8];
#pragma unroll
    for (int q = 0; q < 8; ++q) ed[q] = edges[j + q];
    u32 dw[8];
    float sc[8];
#pragma unroll
    for (int q = 0; q < 8; ++q) {
      dw[q] = Zq[(size_t)ed[q].x * 64 + lane];
      sc[q] = scales[(size_t)ed[q].x * 4 + gsel];
    }
#pragma unroll
    for (int q = 0; q < 8; ++q) {
      const float vs = __int_as_float(ed[q].y) * sc[q];
      a0 += vs * i8f(dw[q], 0);
      a1 += vs * i8f(dw[q], 1);
      a2 += vs * i8f(dw[q], 2);
      a3 += vs * i8f(dw[q], 3);
    }
  }
  for (; j < e; ++j) {
    const int2 e0 = edges[j];
    const u32 dw = Zq[(size_t)e0.x * 64 + lane];
    const float vs =
        __int_as_float(e0.y) * scales[(size_t)e0.x * 4 + gsel];
    a0 += vs * i8f(dw, 0);
    a1 += vs * i8f(dw, 1);
    a2 += vs * i8f(dw, 2);
    a3 += vs * i8f(dw, 3);
  }
  ushort4 o;  // relu + bf16 (output stays in permuted feature order)
  o.x = f2bf(fmaxf(a0, 0.f));
  o.y = f2bf(fmaxf(a1, 0.f));
  o.z = f2bf(fmaxf(a2, 0.f));
  o.w = f2bf(fmaxf(a3, 0.f));
  reinterpret_cast<ushort4*>(Yb + (size_t)wid * 256)[lane] = o;
}

// ---------------------------------------------------------------------------
// CSR SpMM width 64, int8 input (per-row scale), fp32 out (canonical order).
// One wave/row; lane f reads byte f>>4 of dword f&15. unroll 8.
// ---------------------------------------------------------------------------
__global__ __launch_bounds__(256) void spmm64_q8(
    const int* __restrict__ ptr, const int2* __restrict__ edges,
    const u32* __restrict__ Z2q, const float* __restrict__ zsc2,
    float* __restrict__ Y) {
  const int wid = (int)((blockIdx.x * (size_t)256 + threadIdx.x) >> 6);
  const int lane = threadIdx.x & 63;
  if (wid >= NN) return;
  const int s = ptr[wid], e = ptr[wid + 1];
  const int dwi = lane & 15;
  const int byi = lane >> 4;
  float acc = 0.f;
  int j = s;
  for (; j + 7 < e; j += 8) {
    int2 ed[8];
#pragma unroll
    for (int q = 0; q < 8; ++q) ed[q] = edges[j + q];
    u32 dw[8];
    float sc[8];
#pragma unroll
    for (int q = 0; q < 8; ++q) {
      dw[q] = Z2q[(size_t)ed[q].x * 16 + dwi];
      sc[q] = zsc2[ed[q].x];
    }
#pragma unroll
    for (int q = 0; q < 8; ++q)
      acc += __int_as_float(ed[q].y) * sc[q] * i8f(dw[q], byi);
  }
  for (; j < e; ++j) {
    const int2 e0 = edges[j];
    const u32 dw = Z2q[(size_t)e0.x * 16 + dwi];
    acc += __int_as_float(e0.y) * zsc2[e0.x] * i8f(dw, byi);
  }
  Y[(size_t)wid * 64 + lane] = acc;
}

extern "C" void kernel_launch(void* const* d_in, const int* in_sizes, int n_in,
                              void* d_out, int out_size, void* d_ws,
                              size_t ws_size, hipStream_t stream) {
  const float* x_a  = (const float*)d_in[0];
  const float* x_b  = (const float*)d_in[1];
  const int*   rows = (const int*)d_in[2];
  const int*   cols = (const int*)d_in[3];
  const float* vals = (const float*)d_in[4];
  const float* W1a  = (const float*)d_in[5];
  const float* b1a  = (const float*)d_in[6];
  const float* W1b  = (const float*)d_in[7];
  const float* b1b  = (const float*)d_in[8];
  const float* Wf   = (const float*)d_in[9];
  const float* bf   = (const float*)d_in[10];
  const float* W2   = (const float*)d_in[11];
  const float* b2   = (const float*)d_in[12];
  float* out = (float*)d_out;

  // workspace (~155 MB); edges2 aliases xab/xbb (dead after gemm1/2)
  char* p = (char*)d_ws;
  u16* h    = (u16*)p;  p += (size_t)NN * NHID * 2;   // h, later s1b
  u32* zq   = (u32*)p;  p += (size_t)NN * 64 * 4;     // 25.6MB int8 z
  float* zscale = (float*)p; p += (size_t)NN * 4 * 4; // 1.6MB
  u32* z2q  = (u32*)p;  p += (size_t)NN * 16 * 4;     // 6.4MB int8 z2
  float* zsc2 = (float*)p; p += (size_t)NN * 4;       // 0.4MB
  u16* xab  = (u16*)p;  p += (size_t)NA * 256 * 2;    // \ edges2 aliases
  u16* xbb  = (u16*)p;  p += (size_t)NB * 128 * 2;    // /  (40.9MB >= 25.6MB)
  u16* W1at = (u16*)p;  p += 256 * 256 * 2;
  u16* W1bt = (u16*)p;  p += 256 * 128 * 2;
  u16* Wft  = (u16*)p;  p += 256 * 256 * 2;
  u16* W2t  = (u16*)p;  p += 64 * 256 * 2;
  int2* edges = (int2*)p; p += (size_t)NE * 8;
  int* cnt    = (int*)p;  p += (size_t)NBUCK * PBLK * 4;
  int* btot   = (int*)p;  p += (size_t)((NBUCK + 3) & ~3) * 4;
  int* bstart = (int*)p;  p += (size_t)((NBUCK + 4) & ~3) * 4;
  int* rptr   = (int*)p;  p += (size_t)(NN + 4) * 4;
  u16* s1b = h;
  int2* edges2 = (int2*)xab;

  // L1: cvt_a | cvt_b | weight transposes | p1 histogram (all independent)
  prep<<<CVT_BLKS + WT_BLKS + PBLK, 256, 0, stream>>>(
      (const float4*)x_a, (ushort4*)xab, (const float4*)x_b, (ushort4*)xbb,
      W1a, W1b, Wf, W2, W1at, W1bt, Wft, W2t, rows, cnt);

  // L2: gemm1 | gemm2 | s1 scan
  gemm12_s1<<<G1_BLKS + G2_BLKS + NBUCK, 256, 0, stream>>>(
      xab, W1at, b1a, xbb, W1bt, b1b, h, cnt, btot);

  // L3: gemm3 (int8 quant) | s2 scan
  gemm3_s2<<<G3_BLKS + 1, 256, 0, stream>>>(h, Wft, bf, zq, zscale, btot,
                                            bstart);

  // L4/L5: scatter into buckets, then per-bucket row sort (xab/xbb now dead)
  p3_scatter<<<PBLK, 256, 0, stream>>>(rows, cols, vals, cnt, bstart, edges);
  sort_bucket<<<NBUCK, 256, 0, stream>>>(bstart, edges, edges2, rptr);

  // L6: s1b = bf16(relu(spmm(zq)))  (permuted feature order)
  spmm256_q8<<<(NN * 64 + 255) / 256, 256, 0, stream>>>(rptr, edges2, zq,
                                                        zscale, s1b);
  // L7: z2q = int8(s1b @ W2t^T + b2), per-row scale
  gemm_mfma<64, 0, 2><<<dim3((NN + 127) / 128, 1), 256, 0, stream>>>(
      s1b, W2t, b2, z2q, zsc2, NN, NOUT, 256);
  // L8: out = spmm(z2q)  (canonical feature order restored per-lane)
  spmm64_q8<<<(NN * 64 + 255) / 256, 256, 0, stream>>>(rptr, edges2, z2q,
                                                       zsc2, out);
}

// Round 12
// 479.426 us; speedup vs baseline: 1.0680x; 1.0261x over previous
//
#include <hip/hip_runtime.h>

#define NN 100000
#define NE 3200000
#define NA 60000
#define NB 40000
#define NHID 256
#define NOUT 64

#define RPB 64                    // rows per bucket
#define NBUCK 1563                // ceil(NN/64)
#define PBLK 256                  // partition blocks
#define CHUNK 12500               // NE / PBLK (exact)

// prep-kernel block ranges (wt | p1)
#define WT_BLKS 704               // 180224 / 256
// gemm12_s1 block ranges
#define G1_BLKS 938               // 469 * 2
#define G2_BLKS 626               // 313 * 2
// gemm3_s2_p3
#define G3_BLKS 1564              // 782 * 2

typedef unsigned short u16;
typedef unsigned int u32;
typedef __attribute__((ext_vector_type(8))) short short8;
typedef __attribute__((ext_vector_type(4))) float f32x4;

__device__ __forceinline__ float bf2f(u16 u) {
  return __uint_as_float(((u32)u) << 16);
}
__device__ __forceinline__ u16 f2bf(float f) {
  u32 u = __float_as_uint(f);
  u32 r = (u + 0x7fffu + ((u >> 16) & 1u)) >> 16;  // RNE
  return (u16)r;
}
// sign-extend byte b of dw to float
__device__ __forceinline__ float i8f(u32 dw, int b) {
  return (float)((int)(dw << (24 - 8 * b)) >> 24);
}

__device__ __forceinline__ void gload_lds16(const void* gsrc, void* ldst) {
  __builtin_amdgcn_global_load_lds(
      (const __attribute__((address_space(1))) void*)gsrc,
      (__attribute__((address_space(3))) void*)ldst, 16, 0, 0);
}

// ---------------------------------------------------------------------------
// bf16 MFMA GEMM body (bf16 A via global_load_lds). As/Bs: caller LDS.
// QUANT=0: bf16 out (opt relu).
// QUANT=1 (BN=128, N=256): int8 out, per-row-per-64col scale, lane-major pack.
// QUANT=2 (BN=64, N=64): int8 out, per-row scale, lane-major pack.
// ---------------------------------------------------------------------------
template <int BN, int RELU_OUT, int QUANT>
__device__ __forceinline__ void gemm_body(
    int bx, int by, const u16* __restrict__ A, const u16* __restrict__ Bt,
    const float* __restrict__ bias, void* __restrict__ Cout,
    float* __restrict__ scales, int M, int N, int K, u16* As, u16* Bs) {
  constexpr int FI = (BN == 128) ? 4 : 2;
  constexpr int WROWS = FI * 16;

  const int tid = threadIdx.x;
  const int w = tid >> 6;
  const int lane = tid & 63;
  const int bm = bx * 128;
  const int bn = by * BN;
  const int wr = (BN == 128) ? (w >> 1) : w;
  const int wc = (BN == 128) ? (w & 1) : 0;

  f32x4 acc[FI][4];
#pragma unroll
  for (int i = 0; i < FI; ++i)
#pragma unroll
    for (int j = 0; j < 4; ++j) acc[i][j] = (f32x4)0.f;

  for (int k0 = 0; k0 < K; k0 += 32) {
#pragma unroll
    for (int s = 0; s < 2; ++s) {
      const int inst = w * 2 + s;
      const int row = inst * 16 + (lane >> 2);
      int rg = bm + row;
      if (rg > M - 1) rg = M - 1;
      const int c = (lane & 3) ^ ((row >> 1) & 3);
      gload_lds16(A + (size_t)rg * K + k0 + c * 8, &As[inst * 512]);
    }
    if (BN == 128) {
#pragma unroll
      for (int s = 0; s < 2; ++s) {
        const int inst = w * 2 + s;
        const int row = inst * 16 + (lane >> 2);
        const int c = (lane & 3) ^ ((row >> 1) & 3);
        gload_lds16(Bt + (size_t)(bn + row) * K + k0 + c * 8,
                    &Bs[inst * 512]);
      }
    } else {
      const int inst = w;
      const int row = inst * 16 + (lane >> 2);
      const int c = (lane & 3) ^ ((row >> 1) & 3);
      gload_lds16(Bt + (size_t)(bn + row) * K + k0 + c * 8, &Bs[inst * 512]);
    }
    __syncthreads();

    const int kc = lane >> 4;
    short8 af[FI], bfr[4];
#pragma unroll
    for (int i = 0; i < FI; ++i) {
      const int row = wr * WROWS + i * 16 + (lane & 15);
      const int ch = kc ^ ((row >> 1) & 3);
      af[i] = *reinterpret_cast<const short8*>(&As[row * 32 + ch * 8]);
    }
#pragma unroll
    for (int j = 0; j < 4; ++j) {
      const int row = wc * 64 + j * 16 + (lane & 15);
      const int ch = kc ^ ((row >> 1) & 3);
      bfr[j] = *reinterpret_cast<const short8*>(&Bs[row * 32 + ch * 8]);
    }
#pragma unroll
    for (int i = 0; i < FI; ++i)
#pragma unroll
      for (int j = 0; j < 4; ++j)
        acc[i][j] = __builtin_amdgcn_mfma_f32_16x16x32_bf16(af[i], bfr[j],
                                                            acc[i][j], 0, 0, 0);
    __syncthreads();
  }

  if constexpr (QUANT == 1) {
    float bv[4];
#pragma unroll
    for (int j = 0; j < 4; ++j)
      bv[j] = bias[bn + wc * 64 + j * 16 + (lane & 15)];
    const int g = (bn >> 6) + wc;  // 64-col block index 0..3
    u32* zq = (u32*)Cout;
#pragma unroll
    for (int i = 0; i < FI; ++i) {
#pragma unroll
      for (int r = 0; r < 4; ++r) {
        float o[4];
#pragma unroll
        for (int j = 0; j < 4; ++j) o[j] = acc[i][j][r] + bv[j];
        float am = fmaxf(fmaxf(fabsf(o[0]), fabsf(o[1])),
                         fmaxf(fabsf(o[2]), fabsf(o[3])));
#pragma unroll
        for (int mk = 1; mk < 16; mk <<= 1) am = fmaxf(am, __shfl_xor(am, mk));
        const float sinv = am > 0.f ? 127.f / am : 0.f;
        const float scv = am > 0.f ? am / 127.f : 0.f;
        const int q0 = __float2int_rn(o[0] * sinv);
        const int q1 = __float2int_rn(o[1] * sinv);
        const int q2 = __float2int_rn(o[2] * sinv);
        const int q3 = __float2int_rn(o[3] * sinv);
        const u32 dw = (q0 & 0xff) | ((q1 & 0xff) << 8) | ((q2 & 0xff) << 16) |
                       ((q3 & 0xff) << 24);
        const int row = bm + wr * WROWS + i * 16 + (lane >> 4) * 4 + r;
        if (row < M) {
          zq[(size_t)row * 64 + g * 16 + (lane & 15)] = dw;
          if ((lane & 15) == 0) scales[(size_t)row * 4 + g] = scv;
        }
      }
    }
  } else if constexpr (QUANT == 2) {
    float bv[4];
#pragma unroll
    for (int j = 0; j < 4; ++j) bv[j] = bias[j * 16 + (lane & 15)];
    u32* zq = (u32*)Cout;
#pragma unroll
    for (int i = 0; i < FI; ++i) {
#pragma unroll
      for (int r = 0; r < 4; ++r) {
        float o[4];
#pragma unroll
        for (int j = 0; j < 4; ++j) o[j] = acc[i][j][r] + bv[j];
        float am = fmaxf(fmaxf(fabsf(o[0]), fabsf(o[1])),
                         fmaxf(fabsf(o[2]), fabsf(o[3])));
#pragma unroll
        for (int mk = 1; mk < 16; mk <<= 1) am = fmaxf(am, __shfl_xor(am, mk));
        const float sinv = am > 0.f ? 127.f / am : 0.f;
        const float scv = am > 0.f ? am / 127.f : 0.f;
        const int q0 = __float2int_rn(o[0] * sinv);
        const int q1 = __float2int_rn(o[1] * sinv);
        const int q2 = __float2int_rn(o[2] * sinv);
        const int q3 = __float2int_rn(o[3] * sinv);
        const u32 dw = (q0 & 0xff) | ((q1 & 0xff) << 8) | ((q2 & 0xff) << 16) |
                       ((q3 & 0xff) << 24);
        const int row = bm + wr * WROWS + i * 16 + (lane >> 4) * 4 + r;
        if (row < M) {
          zq[(size_t)row * 16 + (lane & 15)] = dw;
          if ((lane & 15) == 0) scales[row] = scv;
        }
      }
    }
  } else {
    u16* C = (u16*)Cout;
#pragma unroll
    for (int i = 0; i < FI; ++i) {
#pragma unroll
      for (int j = 0; j < 4; ++j) {
        const int col = bn + wc * 64 + j * 16 + (lane & 15);
        const float bv = bias[col];
#pragma unroll
        for (int r = 0; r < 4; ++r) {
          const int row = bm + wr * WROWS + i * 16 + (lane >> 4) * 4 + r;
          if (row < M) {
            float o = acc[i][j][r] + bv;
            if (RELU_OUT) o = fmaxf(o, 0.f);
            C[(size_t)row * N + col] = f2bf(o);
          }
        }
      }
    }
  }
}

// ---------------------------------------------------------------------------
// GEMM body variant: A read DIRECTLY as fp32, reg-staged + converted to bf16
// in LDS (same swizzled layout: source chunk c stored at position c^sw).
// BN=128, N=256, relu+bf16 out. Numerics identical to cvt-then-gemm.
// ---------------------------------------------------------------------------
__device__ __forceinline__ void gemm_af32(
    int bx, int by, const float* __restrict__ Af, const u16* __restrict__ Bt,
    const float* __restrict__ bias, u16* __restrict__ C, int M, int K,
    u16* As, u16* Bs) {
  constexpr int N = 256;
  const int tid = threadIdx.x;
  const int w = tid >> 6;
  const int lane = tid & 63;
  const int bm = bx * 128;
  const int bn = by * 128;
  const int wr = w >> 1;
  const int wc = w & 1;

  f32x4 acc[4][4];
#pragma unroll
  for (int i = 0; i < 4; ++i)
#pragma unroll
    for (int j = 0; j < 4; ++j) acc[i][j] = (f32x4)0.f;

  // A staging indices: thread covers row=tid>>1, k-half=tid&1 (16 f32 = 64B)
  const int arow = tid >> 1;
  const int ahalf = tid & 1;
  int arg = bm + arow;
  if (arg > M - 1) arg = M - 1;
  const int asw = (arow >> 1) & 3;

  for (int k0 = 0; k0 < K; k0 += 32) {
    // --- B tile via async global->LDS (bf16, pre-swizzled source) ---
#pragma unroll
    for (int s = 0; s < 2; ++s) {
      const int inst = w * 2 + s;
      const int row = inst * 16 + (lane >> 2);
      const int c = (lane & 3) ^ ((row >> 1) & 3);
      gload_lds16(Bt + (size_t)(bn + row) * K + k0 + c * 8, &Bs[inst * 512]);
    }
    // --- A tile: fp32 global -> regs -> bf16 -> swizzled ds_write ---
    {
      const float4* src = reinterpret_cast<const float4*>(
          Af + (size_t)arg * K + k0 + ahalf * 16);
      const float4 v0 = src[0], v1 = src[1], v2 = src[2], v3 = src[3];
      short8 lo, hi;
      lo[0] = (short)f2bf(v0.x); lo[1] = (short)f2bf(v0.y);
      lo[2] = (short)f2bf(v0.z); lo[3] = (short)f2bf(v0.w);
      lo[4] = (short)f2bf(v1.x); lo[5] = (short)f2bf(v1.y);
      lo[6] = (short)f2bf(v1.z); lo[7] = (short)f2bf(v1.w);
      hi[0] = (short)f2bf(v2.x); hi[1] = (short)f2bf(v2.y);
      hi[2] = (short)f2bf(v2.z); hi[3] = (short)f2bf(v2.w);
      hi[4] = (short)f2bf(v3.x); hi[5] = (short)f2bf(v3.y);
      hi[6] = (short)f2bf(v3.z); hi[7] = (short)f2bf(v3.w);
      short8* dst = reinterpret_cast<short8*>(As + arow * 32);
      dst[(ahalf * 2) ^ asw] = lo;
      dst[(ahalf * 2 + 1) ^ asw] = hi;
    }
    __syncthreads();

    const int kc = lane >> 4;
    short8 af[4], bfr[4];
#pragma unroll
    for (int i = 0; i < 4; ++i) {
      const int row = wr * 64 + i * 16 + (lane & 15);
      const int ch = kc ^ ((row >> 1) & 3);
      af[i] = *reinterpret_cast<const short8*>(&As[row * 32 + ch * 8]);
    }
#pragma unroll
    for (int j = 0; j < 4; ++j) {
      const int row = wc * 64 + j * 16 + (lane & 15);
      const int ch = kc ^ ((row >> 1) & 3);
      bfr[j] = *reinterpret_cast<const short8*>(&Bs[row * 32 + ch * 8]);
    }
#pragma unroll
    for (int i = 0; i < 4; ++i)
#pragma unroll
      for (int j = 0; j < 4; ++j)
        acc[i][j] = __builtin_amdgcn_mfma_f32_16x16x32_bf16(af[i], bfr[j],
                                                            acc[i][j], 0, 0, 0);
    __syncthreads();
  }

  // epilogue: bias + relu -> bf16
#pragma unroll
  for (int i = 0; i < 4; ++i) {
#pragma unroll
    for (int j = 0; j < 4; ++j) {
      const int col = bn + wc * 64 + j * 16 + (lane & 15);
      const float bv = bias[col];
#pragma unroll
      for (int r = 0; r < 4; ++r) {
        const int row = bm + wr * 64 + i * 16 + (lane >> 4) * 4 + r;
        if (row < M) {
          float o = fmaxf(acc[i][j][r] + bv, 0.f);
          C[(size_t)row * N + col] = f2bf(o);
        }
      }
    }
  }
}

// Standalone GEMM wrapper (used for gemm4)
template <int BN, int RELU_OUT, int QUANT>
__global__ __launch_bounds__(256) void gemm_mfma(
    const u16* __restrict__ A, const u16* __restrict__ Bt,
    const float* __restrict__ bias, void* __restrict__ Cout,
    float* __restrict__ scales, int M, int N, int K) {
  __shared__ __align__(16) u16 As[128 * 32];
  __shared__ __align__(16) u16 Bs[BN * 32];
  gemm_body<BN, RELU_OUT, QUANT>(blockIdx.x, blockIdx.y, A, Bt, bias, Cout,
                                 scales, M, N, K, As, Bs);
}

// ---------------------------------------------------------------------------
// L1 prep: weight transposes | p1 bucket histogram
// ---------------------------------------------------------------------------
__global__ __launch_bounds__(256) void prep(
    const float* __restrict__ W1a, const float* __restrict__ W1b,
    const float* __restrict__ Wf, const float* __restrict__ W2,
    u16* __restrict__ W1at, u16* __restrict__ W1bt, u16* __restrict__ Wft,
    u16* __restrict__ W2t, const int* __restrict__ rows,
    int* __restrict__ cnt) {
  __shared__ int hsh[NBUCK];
  const int b = blockIdx.x;
  const int tid = threadIdx.x;
  if (b < WT_BLKS) {
    const int i = b * 256 + tid;
    if (i < 65536) {                       // W1a [256,256] -> [256,256]
      const int n = i >> 8, k = i & 255;
      W1at[i] = f2bf(W1a[k * 256 + n]);
    } else if (i < 98304) {                // W1b [128,256] -> [256,128]
      const int t = i - 65536;
      const int n = t >> 7, k = t & 127;
      W1bt[t] = f2bf(W1b[k * 256 + n]);
    } else if (i < 163840) {               // Wf [256,256] -> [256,256]
      const int t = i - 98304;
      const int n = t >> 8, k = t & 255;
      Wft[t] = f2bf(Wf[k * 256 + n]);
    } else if (i < 180224) {               // W2 [256,64] -> [64,256] permuted
      const int t = i - 163840;
      const int n = t >> 8, p = t & 255;
      const int f = ((p >> 6) << 6) + ((p & 3) << 4) + ((p >> 2) & 15);
      W2t[t] = f2bf(W2[f * 64 + n]);
    }
  } else {
    // p1 histogram, partition block blk in [0, PBLK)
    const int blk = b - WT_BLKS;
    for (int i = tid; i < NBUCK; i += 256) hsh[i] = 0;
    __syncthreads();
    const int s = blk * CHUNK;
    const int e = s + CHUNK;
    for (int i = s + tid; i < e; i += 256) atomicAdd(&hsh[rows[i] >> 6], 1);
    __syncthreads();
    for (int i = tid; i < NBUCK; i += 256) cnt[i * PBLK + blk] = hsh[i];
  }
}

// ---------------------------------------------------------------------------
// L2: gemm1 (fp32 A) | gemm2 (fp32 A) | s1 per-bucket scan of block counts
// ---------------------------------------------------------------------------
__global__ __launch_bounds__(256) void gemm12_s1(
    const float* __restrict__ xa, const u16* __restrict__ W1at,
    const float* __restrict__ b1a, const float* __restrict__ xb,
    const u16* __restrict__ W1bt, const float* __restrict__ b1b,
    u16* __restrict__ h, int* __restrict__ cnt, int* __restrict__ btot) {
  __shared__ __align__(16) u16 As[128 * 32];
  __shared__ __align__(16) u16 Bs[128 * 32];
  const int b = blockIdx.x;
  if (b < G1_BLKS) {
    gemm_af32(b % 469, b / 469, xa, W1at, b1a, h, NA, 256, As, Bs);
  } else if (b < G1_BLKS + G2_BLKS) {
    const int t = b - G1_BLKS;
    gemm_af32(t % 313, t / 313, xb, W1bt, b1b, h + (size_t)NA * NHID, NB, 128,
              As, Bs);
  } else {
    // s1: exclusive scan of cnt[bu][0..255] -> in place, total -> btot[bu]
    int* lds = (int*)As;
    const int bu = b - (G1_BLKS + G2_BLKS);
    const int t = threadIdx.x;
    const int v = cnt[bu * PBLK + t];
    lds[t] = v;
    __syncthreads();
#pragma unroll
    for (int off = 1; off < 256; off <<= 1) {
      const int x = (t >= off) ? lds[t - off] : 0;
      __syncthreads();
      lds[t] += x;
      __syncthreads();
    }
    cnt[bu * PBLK + t] = lds[t] - v;
    if (t == 255) btot[bu] = lds[255];
  }
}

// ---------------------------------------------------------------------------
// L3: gemm3 (int8 quant out) | s2 scan (global bstart) | p3 scatter
// (p3 re-derives bstart locally from btot -- no dependency on s2)
// ---------------------------------------------------------------------------
__global__ __launch_bounds__(256) void gemm3_s2_p3(
    const u16* __restrict__ h, const u16* __restrict__ Wft,
    const float* __restrict__ bfv, u32* __restrict__ zq,
    float* __restrict__ zscale, const int* __restrict__ btot,
    int* __restrict__ bstart, const int* __restrict__ rows,
    const int* __restrict__ cols, const float* __restrict__ vals,
    const int* __restrict__ cnt, int2* __restrict__ edges) {
  __shared__ __align__(16) u16 As[128 * 32];
  __shared__ __align__(16) u16 Bs[128 * 32];
  const int b = blockIdx.x;
  const int t = threadIdx.x;
  if (b < G3_BLKS) {
    gemm_body<128, 0, 1>(b % 782, b / 782, h, Wft, bfv, zq, zscale, NN, NHID,
                         256, As, Bs);
  } else if (b == G3_BLKS) {
    // s2: exclusive scan of btot -> global bstart (for sort_bucket)
    int* lds = (int*)As;
    int carry = 0;
    for (int base = 0; base < NBUCK; base += 256) {
      const int i = base + t;
      const int v = (i < NBUCK) ? btot[i] : 0;
      lds[t] = v;
      __syncthreads();
#pragma unroll
      for (int off = 1; off < 256; off <<= 1) {
        const int x = (t >= off) ? lds[t - off] : 0;
        __syncthreads();
        lds[t] += x;
        __syncthreads();
      }
      const int excl = lds[t] - v;
      const int tot = lds[255];
      if (i < NBUCK) bstart[i] = carry + excl;
      __syncthreads();
      carry += tot;
    }
    if (t == 0) bstart[NBUCK] = NE;
  } else {
    // p3: local bstart scan, then scatter this partition's edge chunk
    const int blk = b - (G3_BLKS + 1);
    int* lbs = (int*)As;   // [NBUCK] local bstart -> cursor
    int* tmp = (int*)Bs;   // [256] scan scratch
    int carry = 0;
    for (int base = 0; base < NBUCK; base += 256) {
      const int i = base + t;
      const int v = (i < NBUCK) ? btot[i] : 0;
      tmp[t] = v;
      __syncthreads();
#pragma unroll
      for (int off = 1; off < 256; off <<= 1) {
        const int x = (t >= off) ? tmp[t - off] : 0;
        __syncthreads();
        tmp[t] += x;
        __syncthreads();
      }
      if (i < NBUCK) lbs[i] = carry + tmp[t] - v;
      const int tot = tmp[255];
      __syncthreads();
      carry += tot;
    }
    // cursor = bstart + this block's exclusive offset within the bucket
    for (int bu = t; bu < NBUCK; bu += 256) lbs[bu] += cnt[bu * PBLK + blk];
    __syncthreads();
    const int s = blk * CHUNK;
    const int e = s + CHUNK;
    for (int i = s + t; i < e; i += 256) {
      const int r = rows[i];
      const int pos = atomicAdd(&lbs[r >> 6], 1);
      edges[pos] = make_int2(cols[i] | ((r & 63) << 17), __float_as_int(vals[i]));
    }
  }
}

// Per-bucket counting sort -> row-sorted edges2 + rptr. One block per bucket.
__global__ __launch_bounds__(256) void sort_bucket(
    const int* __restrict__ bstart, const int2* __restrict__ edges,
    int2* __restrict__ edges2, int* __restrict__ rptr) {
  __shared__ int hist[RPB];
  __shared__ int sc[RPB];
  __shared__ int cur[RPB];
  const int bu = blockIdx.x;
  const int t = threadIdx.x;
  const int s = bstart[bu], e = bstart[bu + 1];
  if (t < RPB) hist[t] = 0;
  __syncthreads();
  for (int i = s + t; i < e; i += 256)
    atomicAdd(&hist[(edges[i].x >> 17) & 63], 1);
  __syncthreads();
  const int hv = (t < RPB) ? hist[t] : 0;
  if (t < RPB) sc[t] = hv;
  __syncthreads();
#pragma unroll
  for (int off = 1; off < RPB; off <<= 1) {
    const int x = (t >= off && t < RPB) ? sc[t - off] : 0;
    __syncthreads();
    if (t < RPB) sc[t] += x;
    __syncthreads();
  }
  if (t < RPB) {
    const int base = s + sc[t] - hv;
    cur[t] = base;
    const int grow = bu * RPB + t;
    if (grow < NN) rptr[grow] = base;
  }
  if (bu == 0 && t == 0) rptr[NN] = NE;
  __syncthreads();
  for (int i = s + t; i < e; i += 256) {
    const int2 ed = edges[i];
    const int lr = (ed.x >> 17) & 63;
    const int pos = atomicAdd(&cur[lr], 1);
    edges2[pos] = make_int2(ed.x & 0x1FFFF, ed.y);
  }
}

// ---------------------------------------------------------------------------
// CSR SpMM width 256, int8 input (per-row-per-64col scale), relu+bf16 out.
// One wave/row, lane = 1 dword (4 features). unroll 8.
// ---------------------------------------------------------------------------
__global__ __launch_bounds__(256) void spmm256_q8(
    const int* __restrict__ ptr, const int2* __restrict__ edges,
    const u32* __restrict__ Zq, const float* __restrict__ scales,
    u16* __restrict__ Yb) {
  const int wid = (int)((blockIdx.x * (size_t)256 + threadIdx.x) >> 6);
  const int lane = threadIdx.x & 63;
  if (wid >= NN) return;
  const int s = ptr[wid], e = ptr[wid + 1];
  const int gsel = lane >> 4;
  float a0 = 0.f, a1 = 0.f, a2 = 0.f, a3 = 0.f;
  int j = s;
  for (; j + 7 < e; j += 8) {
    int2 ed[8];
#pragma unroll
    for (int q = 0; q < 8; ++q) ed[q] = edges[j + q];
    u32 dw[8];
    float sc[8];
#pragma unroll
    for (int q = 0; q < 8; ++q) {
      dw[q] = Zq[(size_t)ed[q].x * 64 + lane];
      sc[q] = scales[(size_t)ed[q].x * 4 + gsel];
    }
#pragma unroll
    for (int q = 0; q < 8; ++q) {
      const float vs = __int_as_float(ed[q].y) * sc[q];
      a0 += vs * i8f(dw[q], 0);
      a1 += vs * i8f(dw[q], 1);
      a2 += vs * i8f(dw[q], 2);
      a3 += vs * i8f(dw[q], 3);
    }
  }
  for (; j < e; ++j) {
    const int2 e0 = edges[j];
    const u32 dw = Zq[(size_t)e0.x * 64 + lane];
    const float vs =
        __int_as_float(e0.y) * scales[(size_t)e0.x * 4 + gsel];
    a0 += vs * i8f(dw, 0);
    a1 += vs * i8f(dw, 1);
    a2 += vs * i8f(dw, 2);
    a3 += vs * i8f(dw, 3);
  }
  ushort4 o;  // relu + bf16 (output stays in permuted feature order)
  o.x = f2bf(fmaxf(a0, 0.f));
  o.y = f2bf(fmaxf(a1, 0.f));
  o.z = f2bf(fmaxf(a2, 0.f));
  o.w = f2bf(fmaxf(a3, 0.f));
  reinterpret_cast<ushort4*>(Yb + (size_t)wid * 256)[lane] = o;
}

// ---------------------------------------------------------------------------
// CSR SpMM width 64, int8 input (per-row scale), fp32 out (canonical order).
// One wave/row; lane f reads byte f>>4 of dword f&15. unroll 8.
// ---------------------------------------------------------------------------
__global__ __launch_bounds__(256) void spmm64_q8(
    const int* __restrict__ ptr, const int2* __restrict__ edges,
    const u32* __restrict__ Z2q, const float* __restrict__ zsc2,
    float* __restrict__ Y) {
  const int wid = (int)((blockIdx.x * (size_t)256 + threadIdx.x) >> 6);
  const int lane = threadIdx.x & 63;
  if (wid >= NN) return;
  const int s = ptr[wid], e = ptr[wid + 1];
  const int dwi = lane & 15;
  const int byi = lane >> 4;
  float acc = 0.f;
  int j = s;
  for (; j + 7 < e; j += 8) {
    int2 ed[8];
#pragma unroll
    for (int q = 0; q < 8; ++q) ed[q] = edges[j + q];
    u32 dw[8];
    float sc[8];
#pragma unroll
    for (int q = 0; q < 8; ++q) {
      dw[q] = Z2q[(size_t)ed[q].x * 16 + dwi];
      sc[q] = zsc2[ed[q].x];
    }
#pragma unroll
    for (int q = 0; q < 8; ++q)
      acc += __int_as_float(ed[q].y) * sc[q] * i8f(dw[q], byi);
  }
  for (; j < e; ++j) {
    const int2 e0 = edges[j];
    const u32 dw = Z2q[(size_t)e0.x * 16 + dwi];
    acc += __int_as_float(e0.y) * zsc2[e0.x] * i8f(dw, byi);
  }
  Y[(size_t)wid * 64 + lane] = acc;
}

extern "C" void kernel_launch(void* const* d_in, const int* in_sizes, int n_in,
                              void* d_out, int out_size, void* d_ws,
                              size_t ws_size, hipStream_t stream) {
  const float* x_a  = (const float*)d_in[0];
  const float* x_b  = (const float*)d_in[1];
  const int*   rows = (const int*)d_in[2];
  const int*   cols = (const int*)d_in[3];
  const float* vals = (const float*)d_in[4];
  const float* W1a  = (const float*)d_in[5];
  const float* b1a  = (const float*)d_in[6];
  const float* W1b  = (const float*)d_in[7];
  const float* b1b  = (const float*)d_in[8];
  const float* Wf   = (const float*)d_in[9];
  const float* bf   = (const float*)d_in[10];
  const float* W2   = (const float*)d_in[11];
  const float* b2   = (const float*)d_in[12];
  float* out = (float*)d_out;

  // workspace (~155 MB); edges2 lives in the old xab/xbb region
  char* p = (char*)d_ws;
  u16* h    = (u16*)p;  p += (size_t)NN * NHID * 2;   // h, later s1b
  u32* zq   = (u32*)p;  p += (size_t)NN * 64 * 4;     // 25.6MB int8 z
  float* zscale = (float*)p; p += (size_t)NN * 4 * 4; // 1.6MB
  u32* z2q  = (u32*)p;  p += (size_t)NN * 16 * 4;     // 6.4MB int8 z2
  float* zsc2 = (float*)p; p += (size_t)NN * 4;       // 0.4MB
  int2* edges2 = (int2*)p; p += (size_t)NE * 8;       // 25.6MB
  u16* W1at = (u16*)p;  p += 256 * 256 * 2;
  u16* W1bt = (u16*)p;  p += 256 * 128 * 2;
  u16* Wft  = (u16*)p;  p += 256 * 256 * 2;
  u16* W2t  = (u16*)p;  p += 64 * 256 * 2;
  int2* edges = (int2*)p; p += (size_t)NE * 8;        // 25.6MB
  int* cnt    = (int*)p;  p += (size_t)NBUCK * PBLK * 4;
  int* btot   = (int*)p;  p += (size_t)((NBUCK + 3) & ~3) * 4;
  int* bstart = (int*)p;  p += (size_t)((NBUCK + 4) & ~3) * 4;
  int* rptr   = (int*)p;  p += (size_t)(NN + 4) * 4;
  u16* s1b = h;

  // L1: weight transposes | p1 histogram
  prep<<<WT_BLKS + PBLK, 256, 0, stream>>>(W1a, W1b, Wf, W2, W1at, W1bt, Wft,
                                           W2t, rows, cnt);

  // L2: gemm1 (fp32 A) | gemm2 (fp32 A) | s1 scan
  gemm12_s1<<<G1_BLKS + G2_BLKS + NBUCK, 256, 0, stream>>>(
      x_a, W1at, b1a, x_b, W1bt, b1b, h, cnt, btot);

  // L3: gemm3 (int8 quant) | s2 scan | p3 scatter (local bstart)
  gemm3_s2_p3<<<G3_BLKS + 1 + PBLK, 256, 0, stream>>>(
      h, Wft, bf, zq, zscale, btot, bstart, rows, cols, vals, cnt, edges);

  // L4: per-bucket row sort
  sort_bucket<<<NBUCK, 256, 0, stream>>>(bstart, edges, edges2, rptr);

  // L5: s1b = bf16(relu(spmm(zq)))  (permuted feature order)
  spmm256_q8<<<(NN * 64 + 255) / 256, 256, 0, stream>>>(rptr, edges2, zq,
                                                        zscale, s1b);
  // L6: z2q = int8(s1b @ W2t^T + b2), per-row scale
  gemm_mfma<64, 0, 2><<<dim3((NN + 127) / 128, 1), 256, 0, stream>>>(
      s1b, W2t, b2, z2q, zsc2, NN, NOUT, 256);
  // L7: out = spmm(z2q)  (canonical feature order restored per-lane)
  spmm64_q8<<<(NN * 64 + 255) / 256, 256, 0, stream>>>(rptr, edges2, z2q,
                                                       zsc2, out);
}

// Round 13
// 422.972 us; speedup vs baseline: 1.2105x; 1.1335x over previous
//
#include <hip/hip_runtime.h>

#define NN 100000
#define NE 3200000
#define NA 60000
#define NB 40000
#define NHID 256
#define NOUT 64

#define RPB 64                    // rows per bucket
#define NBUCK 1563                // ceil(NN/64)
#define PBLK 256                  // partition blocks
#define CHUNK 12500               // NE / PBLK (exact)

#define WT_BLKS 704               // 180224 / 256
#define G1_BLKS 469               // ceil(NA/128), BN=256 single pass
#define G2_BLKS 313               // ceil(NB/128)
#define G3_BLKS 782               // ceil(NN/128)

typedef unsigned short u16;
typedef unsigned int u32;
typedef __attribute__((ext_vector_type(8))) short short8;
typedef __attribute__((ext_vector_type(4))) float f32x4;

__device__ __forceinline__ float bf2f(u16 u) {
  return __uint_as_float(((u32)u) << 16);
}
__device__ __forceinline__ u16 f2bf(float f) {
  u32 u = __float_as_uint(f);
  u32 r = (u + 0x7fffu + ((u >> 16) & 1u)) >> 16;  // RNE
  return (u16)r;
}
__device__ __forceinline__ float i8f(u32 dw, int b) {
  return (float)((int)(dw << (24 - 8 * b)) >> 24);
}
__device__ __forceinline__ u16 f2h(float f) {   // f32 -> f16 bits (RNE)
  _Float16 h = (_Float16)f;
  u16 r;
  __builtin_memcpy(&r, &h, 2);
  return r;
}
__device__ __forceinline__ float h2f(u32 b15) { // 15-bit f16 (sign=0) -> f32
  u16 hb = (u16)b15;
  _Float16 h;
  __builtin_memcpy(&h, &hb, 2);
  return (float)h;
}

__device__ __forceinline__ void gload_lds16(const void* gsrc, void* ldst) {
  __builtin_amdgcn_global_load_lds(
      (const __attribute__((address_space(1))) void*)gsrc,
      (__attribute__((address_space(3))) void*)ldst, 16, 0, 0);
}

// ---------------------------------------------------------------------------
// 8-wave GEMM body: BM=128, BN=N=256, 512 threads (2x4 waves, 64x64 tiles).
// A panel read ONCE (grid_y=1). bf16 A via global_load_lds.
// QUANT=0: relu+bf16 out. QUANT=1: int8 out, per-row-per-64col scale.
// ---------------------------------------------------------------------------
template <int QUANT>
__device__ __forceinline__ void gemm8_body(
    int bx, const u16* __restrict__ A, const u16* __restrict__ Bt,
    const float* __restrict__ bias, void* __restrict__ Cout,
    float* __restrict__ scales, int M, int K, u16* As, u16* Bs) {
  const int tid = threadIdx.x;
  const int w = tid >> 6;
  const int lane = tid & 63;
  const int bm = bx * 128;
  const int wr = w >> 2;   // 0..1
  const int wc = w & 3;    // 0..3

  f32x4 acc[4][4];
#pragma unroll
  for (int i = 0; i < 4; ++i)
#pragma unroll
    for (int j = 0; j < 4; ++j) acc[i][j] = (f32x4)0.f;

  for (int k0 = 0; k0 < K; k0 += 32) {
    // A tile [128][32]: 8 insts, one per wave
    {
      const int row = w * 16 + (lane >> 2);
      int rg = bm + row;
      if (rg > M - 1) rg = M - 1;
      const int c = (lane & 3) ^ ((row >> 1) & 3);
      gload_lds16(A + (size_t)rg * K + k0 + c * 8, &As[w * 512]);
    }
    // B tile [256][32]: 16 insts, two per wave
#pragma unroll
    for (int s = 0; s < 2; ++s) {
      const int inst = w * 2 + s;
      const int row = inst * 16 + (lane >> 2);
      const int c = (lane & 3) ^ ((row >> 1) & 3);
      gload_lds16(Bt + (size_t)row * K + k0 + c * 8, &Bs[inst * 512]);
    }
    __syncthreads();

    const int kc = lane >> 4;
    short8 af[4], bfr[4];
#pragma unroll
    for (int i = 0; i < 4; ++i) {
      const int row = wr * 64 + i * 16 + (lane & 15);
      const int ch = kc ^ ((row >> 1) & 3);
      af[i] = *reinterpret_cast<const short8*>(&As[row * 32 + ch * 8]);
    }
#pragma unroll
    for (int j = 0; j < 4; ++j) {
      const int row = wc * 64 + j * 16 + (lane & 15);
      const int ch = kc ^ ((row >> 1) & 3);
      bfr[j] = *reinterpret_cast<const short8*>(&Bs[row * 32 + ch * 8]);
    }
#pragma unroll
    for (int i = 0; i < 4; ++i)
#pragma unroll
      for (int j = 0; j < 4; ++j)
        acc[i][j] = __builtin_amdgcn_mfma_f32_16x16x32_bf16(af[i], bfr[j],
                                                            acc[i][j], 0, 0, 0);
    __syncthreads();
  }

  if constexpr (QUANT == 1) {
    float bv[4];
#pragma unroll
    for (int j = 0; j < 4; ++j) bv[j] = bias[wc * 64 + j * 16 + (lane & 15)];
    const int g = wc;
    u32* zq = (u32*)Cout;
#pragma unroll
    for (int i = 0; i < 4; ++i) {
#pragma unroll
      for (int r = 0; r < 4; ++r) {
        float o[4];
#pragma unroll
        for (int j = 0; j < 4; ++j) o[j] = acc[i][j][r] + bv[j];
        float am = fmaxf(fmaxf(fabsf(o[0]), fabsf(o[1])),
                         fmaxf(fabsf(o[2]), fabsf(o[3])));
#pragma unroll
        for (int mk = 1; mk < 16; mk <<= 1) am = fmaxf(am, __shfl_xor(am, mk));
        const float sinv = am > 0.f ? 127.f / am : 0.f;
        const float scv = am > 0.f ? am / 127.f : 0.f;
        const int q0 = __float2int_rn(o[0] * sinv);
        const int q1 = __float2int_rn(o[1] * sinv);
        const int q2 = __float2int_rn(o[2] * sinv);
        const int q3 = __float2int_rn(o[3] * sinv);
        const u32 dw = (q0 & 0xff) | ((q1 & 0xff) << 8) | ((q2 & 0xff) << 16) |
                       ((q3 & 0xff) << 24);
        const int row = bm + wr * 64 + i * 16 + (lane >> 4) * 4 + r;
        if (row < M) {
          zq[(size_t)row * 64 + g * 16 + (lane & 15)] = dw;
          if ((lane & 15) == 0) scales[(size_t)row * 4 + g] = scv;
        }
      }
    }
  } else {
    u16* C = (u16*)Cout;
#pragma unroll
    for (int i = 0; i < 4; ++i) {
#pragma unroll
      for (int j = 0; j < 4; ++j) {
        const int col = wc * 64 + j * 16 + (lane & 15);
        const float bv = bias[col];
#pragma unroll
        for (int r = 0; r < 4; ++r) {
          const int row = bm + wr * 64 + i * 16 + (lane >> 4) * 4 + r;
          if (row < M) {
            float o = fmaxf(acc[i][j][r] + bv, 0.f);
            C[(size_t)row * 256 + col] = f2bf(o);
          }
        }
      }
    }
  }
}

// ---------------------------------------------------------------------------
// 8-wave GEMM, A read directly as fp32 (reg-staged -> bf16 -> swizzled LDS).
// BM=128, BN=N=256, relu+bf16 out. Same swizzle relation as gload path.
// ---------------------------------------------------------------------------
__device__ __forceinline__ void gemm8_af32(
    int bx, const float* __restrict__ Af, const u16* __restrict__ Bt,
    const float* __restrict__ bias, u16* __restrict__ C, int M, int K,
    u16* As, u16* Bs) {
  const int tid = threadIdx.x;
  const int w = tid >> 6;
  const int lane = tid & 63;
  const int bm = bx * 128;
  const int wr = w >> 2;
  const int wc = w & 3;

  f32x4 acc[4][4];
#pragma unroll
  for (int i = 0; i < 4; ++i)
#pragma unroll
    for (int j = 0; j < 4; ++j) acc[i][j] = (f32x4)0.f;

  // A staging: thread -> row=tid>>2, k-quarter=tid&3 (8 f32 = one 16B chunk)
  const int arow = tid >> 2;
  const int aq = tid & 3;
  int arg = bm + arow;
  if (arg > M - 1) arg = M - 1;
  const int asw = (arow >> 1) & 3;

  for (int k0 = 0; k0 < K; k0 += 32) {
#pragma unroll
    for (int s = 0; s < 2; ++s) {
      const int inst = w * 2 + s;
      const int row = inst * 16 + (lane >> 2);
      const int c = (lane & 3) ^ ((row >> 1) & 3);
      gload_lds16(Bt + (size_t)row * K + k0 + c * 8, &Bs[inst * 512]);
    }
    {
      const float4* src =
          reinterpret_cast<const float4*>(Af + (size_t)arg * K + k0 + aq * 8);
      const float4 v0 = src[0], v1 = src[1];
      short8 ch;
      ch[0] = (short)f2bf(v0.x); ch[1] = (short)f2bf(v0.y);
      ch[2] = (short)f2bf(v0.z); ch[3] = (short)f2bf(v0.w);
      ch[4] = (short)f2bf(v1.x); ch[5] = (short)f2bf(v1.y);
      ch[6] = (short)f2bf(v1.z); ch[7] = (short)f2bf(v1.w);
      reinterpret_cast<short8*>(As + arow * 32)[aq ^ asw] = ch;
    }
    __syncthreads();

    const int kc = lane >> 4;
    short8 af[4], bfr[4];
#pragma unroll
    for (int i = 0; i < 4; ++i) {
      const int row = wr * 64 + i * 16 + (lane & 15);
      const int ch = kc ^ ((row >> 1) & 3);
      af[i] = *reinterpret_cast<const short8*>(&As[row * 32 + ch * 8]);
    }
#pragma unroll
    for (int j = 0; j < 4; ++j) {
      const int row = wc * 64 + j * 16 + (lane & 15);
      const int ch = kc ^ ((row >> 1) & 3);
      bfr[j] = *reinterpret_cast<const short8*>(&Bs[row * 32 + ch * 8]);
    }
#pragma unroll
    for (int i = 0; i < 4; ++i)
#pragma unroll
      for (int j = 0; j < 4; ++j)
        acc[i][j] = __builtin_amdgcn_mfma_f32_16x16x32_bf16(af[i], bfr[j],
                                                            acc[i][j], 0, 0, 0);
    __syncthreads();
  }

#pragma unroll
  for (int i = 0; i < 4; ++i) {
#pragma unroll
    for (int j = 0; j < 4; ++j) {
      const int col = wc * 64 + j * 16 + (lane & 15);
      const float bv = bias[col];
#pragma unroll
      for (int r = 0; r < 4; ++r) {
        const int row = bm + wr * 64 + i * 16 + (lane >> 4) * 4 + r;
        if (row < M) {
          float o = fmaxf(acc[i][j][r] + bv, 0.f);
          C[(size_t)row * 256 + col] = f2bf(o);
        }
      }
    }
  }
}

// ---------------------------------------------------------------------------
// 4-wave GEMM (gemm4 only): BN=64, int8 out per-row scale (QUANT=2 path).
// ---------------------------------------------------------------------------
__global__ __launch_bounds__(256) void gemm4_q8(
    const u16* __restrict__ A, const u16* __restrict__ Bt,
    const float* __restrict__ bias, u32* __restrict__ zq,
    float* __restrict__ scales, int M, int K) {
  __shared__ __align__(16) u16 As[128 * 32];
  __shared__ __align__(16) u16 Bs[64 * 32];
  const int tid = threadIdx.x;
  const int w = tid >> 6;
  const int lane = tid & 63;
  const int bm = blockIdx.x * 128;

  f32x4 acc[2][4];
#pragma unroll
  for (int i = 0; i < 2; ++i)
#pragma unroll
    for (int j = 0; j < 4; ++j) acc[i][j] = (f32x4)0.f;

  for (int k0 = 0; k0 < K; k0 += 32) {
#pragma unroll
    for (int s = 0; s < 2; ++s) {
      const int inst = w * 2 + s;
      const int row = inst * 16 + (lane >> 2);
      int rg = bm + row;
      if (rg > M - 1) rg = M - 1;
      const int c = (lane & 3) ^ ((row >> 1) & 3);
      gload_lds16(A + (size_t)rg * K + k0 + c * 8, &As[inst * 512]);
    }
    {
      const int row = w * 16 + (lane >> 2);
      const int c = (lane & 3) ^ ((row >> 1) & 3);
      gload_lds16(Bt + (size_t)row * K + k0 + c * 8, &Bs[w * 512]);
    }
    __syncthreads();

    const int kc = lane >> 4;
    short8 af[2], bfr[4];
#pragma unroll
    for (int i = 0; i < 2; ++i) {
      const int row = w * 32 + i * 16 + (lane & 15);
      const int ch = kc ^ ((row >> 1) & 3);
      af[i] = *reinterpret_cast<const short8*>(&As[row * 32 + ch * 8]);
    }
#pragma unroll
    for (int j = 0; j < 4; ++j) {
      const int row = j * 16 + (lane & 15);
      const int ch = kc ^ ((row >> 1) & 3);
      bfr[j] = *reinterpret_cast<const short8*>(&Bs[row * 32 + ch * 8]);
    }
#pragma unroll
    for (int i = 0; i < 2; ++i)
#pragma unroll
      for (int j = 0; j < 4; ++j)
        acc[i][j] = __builtin_amdgcn_mfma_f32_16x16x32_bf16(af[i], bfr[j],
                                                            acc[i][j], 0, 0, 0);
    __syncthreads();
  }

  float bv[4];
#pragma unroll
  for (int j = 0; j < 4; ++j) bv[j] = bias[j * 16 + (lane & 15)];
#pragma unroll
  for (int i = 0; i < 2; ++i) {
#pragma unroll
    for (int r = 0; r < 4; ++r) {
      float o[4];
#pragma unroll
      for (int j = 0; j < 4; ++j) o[j] = acc[i][j][r] + bv[j];
      float am = fmaxf(fmaxf(fabsf(o[0]), fabsf(o[1])),
                       fmaxf(fabsf(o[2]), fabsf(o[3])));
#pragma unroll
      for (int mk = 1; mk < 16; mk <<= 1) am = fmaxf(am, __shfl_xor(am, mk));
      const float sinv = am > 0.f ? 127.f / am : 0.f;
      const float scv = am > 0.f ? am / 127.f : 0.f;
      const int q0 = __float2int_rn(o[0] * sinv);
      const int q1 = __float2int_rn(o[1] * sinv);
      const int q2 = __float2int_rn(o[2] * sinv);
      const int q3 = __float2int_rn(o[3] * sinv);
      const u32 dw = (q0 & 0xff) | ((q1 & 0xff) << 8) | ((q2 & 0xff) << 16) |
                     ((q3 & 0xff) << 24);
      const int row = bm + w * 32 + i * 16 + (lane >> 4) * 4 + r;
      if (row < M) {
        zq[(size_t)row * 16 + (lane & 15)] = dw;
        if ((lane & 15) == 0) scales[row] = scv;
      }
    }
  }
}

// ---------------------------------------------------------------------------
// L1 prep: weight transposes | p1 bucket histogram (256 threads)
// ---------------------------------------------------------------------------
__global__ __launch_bounds__(256) void prep(
    const float* __restrict__ W1a, const float* __restrict__ W1b,
    const float* __restrict__ Wf, const float* __restrict__ W2,
    u16* __restrict__ W1at, u16* __restrict__ W1bt, u16* __restrict__ Wft,
    u16* __restrict__ W2t, const int* __restrict__ rows,
    int* __restrict__ cnt) {
  __shared__ int hsh[NBUCK];
  const int b = blockIdx.x;
  const int tid = threadIdx.x;
  if (b < WT_BLKS) {
    const int i = b * 256 + tid;
    if (i < 65536) {
      const int n = i >> 8, k = i & 255;
      W1at[i] = f2bf(W1a[k * 256 + n]);
    } else if (i < 98304) {
      const int t = i - 65536;
      const int n = t >> 7, k = t & 127;
      W1bt[t] = f2bf(W1b[k * 256 + n]);
    } else if (i < 163840) {
      const int t = i - 98304;
      const int n = t >> 8, k = t & 255;
      Wft[t] = f2bf(Wf[k * 256 + n]);
    } else if (i < 180224) {
      const int t = i - 163840;
      const int n = t >> 8, p = t & 255;
      const int f = ((p >> 6) << 6) + ((p & 3) << 4) + ((p >> 2) & 15);
      W2t[t] = f2bf(W2[f * 64 + n]);
    }
  } else {
    const int blk = b - WT_BLKS;
    for (int i = tid; i < NBUCK; i += 256) hsh[i] = 0;
    __syncthreads();
    const int s = blk * CHUNK;
    const int e = s + CHUNK;
    for (int i = s + tid; i < e; i += 256) atomicAdd(&hsh[rows[i] >> 6], 1);
    __syncthreads();
    for (int i = tid; i < NBUCK; i += 256) cnt[i * PBLK + blk] = hsh[i];
  }
}

// ---------------------------------------------------------------------------
// L2 (512 thr): gemm1 (fp32 A) | gemm2 (fp32 A) | s1 per-bucket scan
// ---------------------------------------------------------------------------
__global__ __launch_bounds__(512) void gemm12_s1(
    const float* __restrict__ xa, const u16* __restrict__ W1at,
    const float* __restrict__ b1a, const float* __restrict__ xb,
    const u16* __restrict__ W1bt, const float* __restrict__ b1b,
    u16* __restrict__ h, int* __restrict__ cnt, int* __restrict__ btot) {
  __shared__ __align__(16) u16 As[128 * 32];
  __shared__ __align__(16) u16 Bs[256 * 32];
  const int b = blockIdx.x;
  if (b < G1_BLKS) {
    gemm8_af32(b, xa, W1at, b1a, h, NA, 256, As, Bs);
  } else if (b < G1_BLKS + G2_BLKS) {
    gemm8_af32(b - G1_BLKS, xb, W1bt, b1b, h + (size_t)NA * NHID, NB, 128, As,
               Bs);
  } else {
    int* lds = (int*)As;  // 2048 ints capacity
    const int bu = b - (G1_BLKS + G2_BLKS);
    const int t = threadIdx.x;
    const int v = (t < PBLK) ? cnt[bu * PBLK + t] : 0;
    lds[t] = v;
    __syncthreads();
#pragma unroll
    for (int off = 1; off < PBLK; off <<= 1) {
      const int x = (t >= off) ? lds[t - off] : 0;
      __syncthreads();
      lds[t] += x;
      __syncthreads();
    }
    if (t < PBLK) cnt[bu * PBLK + t] = lds[t] - v;
    if (t == PBLK - 1) btot[bu] = lds[t];
  }
}

// ---------------------------------------------------------------------------
// L3 (512 thr): gemm3 (int8 quant) | s2 scan (global bstart) | p3 scatter
// ---------------------------------------------------------------------------
__global__ __launch_bounds__(512) void gemm3_s2_p3(
    const u16* __restrict__ h, const u16* __restrict__ Wft,
    const float* __restrict__ bfv, u32* __restrict__ zq,
    float* __restrict__ zscale, const int* __restrict__ btot,
    int* __restrict__ bstart, const int* __restrict__ rows,
    const int* __restrict__ cols, const float* __restrict__ vals,
    const int* __restrict__ cnt, int2* __restrict__ edges) {
  __shared__ __align__(16) u16 As[128 * 32];
  __shared__ __align__(16) u16 Bs[256 * 32];
  const int b = blockIdx.x;
  const int t = threadIdx.x;
  if (b < G3_BLKS) {
    gemm8_body<1>(b, h, Wft, bfv, zq, zscale, NN, 256, As, Bs);
  } else if (b == G3_BLKS) {
    int* lds = (int*)As;
    int carry = 0;
    for (int base = 0; base < NBUCK; base += 512) {
      const int i = base + t;
      const int v = (i < NBUCK) ? btot[i] : 0;
      lds[t] = v;
      __syncthreads();
#pragma unroll
      for (int off = 1; off < 512; off <<= 1) {
        const int x = (t >= off) ? lds[t - off] : 0;
        __syncthreads();
        lds[t] += x;
        __syncthreads();
      }
      const int excl = lds[t] - v;
      const int tot = lds[511];
      if (i < NBUCK) bstart[i] = carry + excl;
      __syncthreads();
      carry += tot;
    }
    if (t == 0) bstart[NBUCK] = NE;
  } else {
    const int blk = b - (G3_BLKS + 1);
    int* lbs = (int*)As;  // NBUCK <= 2048 ints
    int* tmp = (int*)Bs;  // 512 ints
    int carry = 0;
    for (int base = 0; base < NBUCK; base += 512) {
      const int i = base + t;
      const int v = (i < NBUCK) ? btot[i] : 0;
      tmp[t] = v;
      __syncthreads();
#pragma unroll
      for (int off = 1; off < 512; off <<= 1) {
        const int x = (t >= off) ? tmp[t - off] : 0;
        __syncthreads();
        tmp[t] += x;
        __syncthreads();
      }
      if (i < NBUCK) lbs[i] = carry + tmp[t] - v;
      const int tot = tmp[511];
      __syncthreads();
      carry += tot;
    }
    for (int bu = t; bu < NBUCK; bu += 512) lbs[bu] += cnt[bu * PBLK + blk];
    __syncthreads();
    const int s = blk * CHUNK;
    const int e = s + CHUNK;
    for (int i = s + t; i < e; i += 512) {
      const int r = rows[i];
      const int pos = atomicAdd(&lbs[r >> 6], 1);
      edges[pos] =
          make_int2(cols[i] | ((r & 63) << 17), __float_as_int(vals[i]));
    }
  }
}

// ---------------------------------------------------------------------------
// L4: per-bucket counting sort -> row-sorted 4B edge records + rptr.
// edges2 word = col(17b) | f16(val) sans sign (15b) << 17.
// ---------------------------------------------------------------------------
__global__ __launch_bounds__(256) void sort_bucket(
    const int* __restrict__ bstart, const int2* __restrict__ edges,
    u32* __restrict__ edges2, int* __restrict__ rptr) {
  __shared__ int hist[RPB];
  __shared__ int sc[RPB];
  __shared__ int cur[RPB];
  const int bu = blockIdx.x;
  const int t = threadIdx.x;
  const int s = bstart[bu], e = bstart[bu + 1];
  if (t < RPB) hist[t] = 0;
  __syncthreads();
  for (int i = s + t; i < e; i += 256)
    atomicAdd(&hist[(edges[i].x >> 17) & 63], 1);
  __syncthreads();
  const int hv = (t < RPB) ? hist[t] : 0;
  if (t < RPB) sc[t] = hv;
  __syncthreads();
#pragma unroll
  for (int off = 1; off < RPB; off <<= 1) {
    const int x = (t >= off && t < RPB) ? sc[t - off] : 0;
    __syncthreads();
    if (t < RPB) sc[t] += x;
    __syncthreads();
  }
  if (t < RPB) {
    const int base = s + sc[t] - hv;
    cur[t] = base;
    const int grow = bu * RPB + t;
    if (grow < NN) rptr[grow] = base;
  }
  if (bu == 0 && t == 0) rptr[NN] = NE;
  __syncthreads();
  for (int i = s + t; i < e; i += 256) {
    const int2 ed = edges[i];
    const int lr = (ed.x >> 17) & 63;
    const int pos = atomicAdd(&cur[lr], 1);
    edges2[pos] = (u32)(ed.x & 0x1FFFF) |
                  ((u32)f2h(__int_as_float(ed.y)) << 17);
  }
}

// ---------------------------------------------------------------------------
// L5: CSR SpMM width 256, int8 payload, 4B edges, relu+bf16 out. unroll 8.
// ---------------------------------------------------------------------------
__global__ __launch_bounds__(256) void spmm256_q8(
    const int* __restrict__ ptr, const u32* __restrict__ edges,
    const u32* __restrict__ Zq, const float* __restrict__ scales,
    u16* __restrict__ Yb) {
  const int wid = (int)((blockIdx.x * (size_t)256 + threadIdx.x) >> 6);
  const int lane = threadIdx.x & 63;
  if (wid >= NN) return;
  const int s = ptr[wid], e = ptr[wid + 1];
  const int gsel = lane >> 4;
  float a0 = 0.f, a1 = 0.f, a2 = 0.f, a3 = 0.f;
  int j = s;
  for (; j + 7 < e; j += 8) {
    u32 ed[8];
#pragma unroll
    for (int q = 0; q < 8; ++q) ed[q] = edges[j + q];
    u32 dw[8];
    float sc[8];
#pragma unroll
    for (int q = 0; q < 8; ++q) {
      const int c = ed[q] & 0x1FFFF;
      dw[q] = Zq[(size_t)c * 64 + lane];
      sc[q] = scales[(size_t)c * 4 + gsel];
    }
#pragma unroll
    for (int q = 0; q < 8; ++q) {
      const float vs = h2f(ed[q] >> 17) * sc[q];
      a0 += vs * i8f(dw[q], 0);
      a1 += vs * i8f(dw[q], 1);
      a2 += vs * i8f(dw[q], 2);
      a3 += vs * i8f(dw[q], 3);
    }
  }
  for (; j < e; ++j) {
    const u32 ed = edges[j];
    const int c = ed & 0x1FFFF;
    const u32 dw = Zq[(size_t)c * 64 + lane];
    const float vs = h2f(ed >> 17) * scales[(size_t)c * 4 + gsel];
    a0 += vs * i8f(dw, 0);
    a1 += vs * i8f(dw, 1);
    a2 += vs * i8f(dw, 2);
    a3 += vs * i8f(dw, 3);
  }
  ushort4 o;
  o.x = f2bf(fmaxf(a0, 0.f));
  o.y = f2bf(fmaxf(a1, 0.f));
  o.z = f2bf(fmaxf(a2, 0.f));
  o.w = f2bf(fmaxf(a3, 0.f));
  reinterpret_cast<ushort4*>(Yb + (size_t)wid * 256)[lane] = o;
}

// ---------------------------------------------------------------------------
// L7: CSR SpMM width 64, int8 payload, 4B edges, fp32 out. unroll 8.
// ---------------------------------------------------------------------------
__global__ __launch_bounds__(256) void spmm64_q8(
    const int* __restrict__ ptr, const u32* __restrict__ edges,
    const u32* __restrict__ Z2q, const float* __restrict__ zsc2,
    float* __restrict__ Y) {
  const int wid = (int)((blockIdx.x * (size_t)256 + threadIdx.x) >> 6);
  const int lane = threadIdx.x & 63;
  if (wid >= NN) return;
  const int s = ptr[wid], e = ptr[wid + 1];
  const int dwi = lane & 15;
  const int byi = lane >> 4;
  float acc = 0.f;
  int j = s;
  for (; j + 7 < e; j += 8) {
    u32 ed[8];
#pragma unroll
    for (int q = 0; q < 8; ++q) ed[q] = edges[j + q];
    u32 dw[8];
    float sc[8];
#pragma unroll
    for (int q = 0; q < 8; ++q) {
      const int c = ed[q] & 0x1FFFF;
      dw[q] = Z2q[(size_t)c * 16 + dwi];
      sc[q] = zsc2[c];
    }
#pragma unroll
    for (int q = 0; q < 8; ++q)
      acc += h2f(ed[q] >> 17) * sc[q] * i8f(dw[q], byi);
  }
  for (; j < e; ++j) {
    const u32 ed = edges[j];
    const int c = ed & 0x1FFFF;
    acc += h2f(ed >> 17) * zsc2[c] * i8f(Z2q[(size_t)c * 16 + dwi], byi);
  }
  Y[(size_t)wid * 64 + lane] = acc;
}

extern "C" void kernel_launch(void* const* d_in, const int* in_sizes, int n_in,
                              void* d_out, int out_size, void* d_ws,
                              size_t ws_size, hipStream_t stream) {
  const float* x_a  = (const float*)d_in[0];
  const float* x_b  = (const float*)d_in[1];
  const int*   rows = (const int*)d_in[2];
  const int*   cols = (const int*)d_in[3];
  const float* vals = (const float*)d_in[4];
  const float* W1a  = (const float*)d_in[5];
  const float* b1a  = (const float*)d_in[6];
  const float* W1b  = (const float*)d_in[7];
  const float* b1b  = (const float*)d_in[8];
  const float* Wf   = (const float*)d_in[9];
  const float* bf   = (const float*)d_in[10];
  const float* W2   = (const float*)d_in[11];
  const float* b2   = (const float*)d_in[12];
  float* out = (float*)d_out;

  // workspace (~130 MB)
  char* p = (char*)d_ws;
  u16* h    = (u16*)p;  p += (size_t)NN * NHID * 2;   // 51.2MB (h, later s1b)
  u32* zq   = (u32*)p;  p += (size_t)NN * 64 * 4;     // 25.6MB int8 z
  float* zscale = (float*)p; p += (size_t)NN * 4 * 4; // 1.6MB
  u32* z2q  = (u32*)p;  p += (size_t)NN * 16 * 4;     // 6.4MB int8 z2
  float* zsc2 = (float*)p; p += (size_t)NN * 4;       // 0.4MB
  u32* edges2 = (u32*)p;  p += (size_t)NE * 4;        // 12.8MB (4B records)
  u16* W1at = (u16*)p;  p += 256 * 256 * 2;
  u16* W1bt = (u16*)p;  p += 256 * 128 * 2;
  u16* Wft  = (u16*)p;  p += 256 * 256 * 2;
  u16* W2t  = (u16*)p;  p += 64 * 256 * 2;
  int2* edges = (int2*)p; p += (size_t)NE * 8;        // 25.6MB
  int* cnt    = (int*)p;  p += (size_t)NBUCK * PBLK * 4;
  int* btot   = (int*)p;  p += (size_t)((NBUCK + 3) & ~3) * 4;
  int* bstart = (int*)p;  p += (size_t)((NBUCK + 4) & ~3) * 4;
  int* rptr   = (int*)p;  p += (size_t)(NN + 4) * 4;
  u16* s1b = h;

  // L1: weight transposes | p1 histogram
  prep<<<WT_BLKS + PBLK, 256, 0, stream>>>(W1a, W1b, Wf, W2, W1at, W1bt, Wft,
                                           W2t, rows, cnt);

  // L2: gemm1 | gemm2 (fp32 A, BN=256 single-pass) | s1 scan
  gemm12_s1<<<G1_BLKS + G2_BLKS + NBUCK, 512, 0, stream>>>(
      x_a, W1at, b1a, x_b, W1bt, b1b, h, cnt, btot);

  // L3: gemm3 (int8 quant, BN=256 single-pass) | s2 | p3 scatter
  gemm3_s2_p3<<<G3_BLKS + 1 + PBLK, 512, 0, stream>>>(
      h, Wft, bf, zq, zscale, btot, bstart, rows, cols, vals, cnt, edges);

  // L4: per-bucket row sort -> 4B edge records
  sort_bucket<<<NBUCK, 256, 0, stream>>>(bstart, edges, edges2, rptr);

  // L5: s1b = bf16(relu(spmm(zq)))  (permuted feature order)
  spmm256_q8<<<(NN * 64 + 255) / 256, 256, 0, stream>>>(rptr, edges2, zq,
                                                        zscale, s1b);
  // L6: z2q = int8(s1b @ W2t^T + b2), per-row scale
  gemm4_q8<<<G3_BLKS, 256, 0, stream>>>(s1b, W2t, b2, z2q, zsc2, NN, 256);
  // L7: out = spmm(z2q)
  spmm64_q8<<<(NN * 64 + 255) / 256, 256, 0, stream>>>(rptr, edges2, z2q,
                                                       zsc2, out);
}